// Round 1
// baseline (1780.366 us; speedup 1.0000x reference)
//
#include <hip/hip_runtime.h>
#include <hip/hip_bf16.h>
#include <stdint.h>

// ---------------------------------------------------------------------------
// HierarchicalHAMT forward on MI355X.
// Key structural insight: the memory scan is LINEAR -> closed-form coefficient
// GEMMs instead of a 2048-step sequential scan. Attention reads only the
// INITIAL fast0/slow0 states, so everything is parallel GEMMs + small fused
// kernels. All large GEMMs: bf16 MFMA 16x16x32, f32 accumulate.
// MFMA layout assumptions (guide-verified):
//   A: lane holds A[m=lane&15][k=(lane>>4)*8+j], j=0..7 (contiguous K)
//   B: lane holds B[k=(lane>>4)*8+j][n=lane&15]
//   D: elem r -> C[row=(lane>>4)*4+r][col=lane&15]
// ---------------------------------------------------------------------------

typedef __hip_bfloat16 bf16;
typedef float f32x4 __attribute__((ext_vector_type(4)));
typedef short s16x8 __attribute__((ext_vector_type(8)));
typedef short s16x4 __attribute__((ext_vector_type(4)));

#define DEV __device__ __forceinline__

static constexpr int S_ = 2048, H_ = 1024, D_ = 512, I_ = 4096, V_ = 32000;
static constexpr int SLn = 32, Lc = 2;
static constexpr size_t LOGITS_N = (size_t)S_ * V_;

DEV float gelu_f(float x) {
    float x3 = x * x * x;
    return 0.5f * x * (1.f + tanhf(0.7978845608028654f * (x + 0.044715f * x3)));
}

#define AS1(p) ((const __attribute__((address_space(1))) void*)(uintptr_t)(p))
#define AS3(p) ((__attribute__((address_space(3))) void*)(uint32_t)(uintptr_t)(p))

// ------------------------------ GEMM (NT) ----------------------------------
// C[M,N] = A[M,K] @ BT[N,K]^T  (+bias, +gelu), A/BT bf16 row-major (lda=ldb=K)
// FLAGS: 1=bias, 2=gelu, 4=store f32, 8=store bf16
template <int FLAGS>
__global__ __launch_bounds__(256) void gemm_nt(const bf16* __restrict__ A,
                                               const bf16* __restrict__ BT,
                                               const float* __restrict__ bias,
                                               float* __restrict__ Cf, int ldf,
                                               bf16* __restrict__ Cb, int ldb2,
                                               int K) {
    __shared__ short As[128 * 32];
    __shared__ short Bs[128 * 32];
    const int tid = threadIdx.x;
    const int lane = tid & 63;
    const int wm = (tid >> 6) >> 1, wn = (tid >> 6) & 1;
    const int m0 = blockIdx.y * 128, n0 = blockIdx.x * 128;

    f32x4 acc[4][4];
#pragma unroll
    for (int i = 0; i < 4; i++)
#pragma unroll
        for (int j = 0; j < 4; j++)
#pragma unroll
            for (int r = 0; r < 4; r++) acc[i][j][r] = 0.f;

    const int nk = K >> 5;
    for (int kt = 0; kt < nk; ++kt) {
        if (kt) __syncthreads();
        // stage A,B tiles: 512 chunks of 16B each per tile, 2 per thread
#pragma unroll
        for (int h = 0; h < 2; ++h) {
            int j = tid + h * 256;
            int row = j >> 2, kc = j & 3;
            const bf16* ga = A + (size_t)(m0 + row) * K + kt * 32 + kc * 8;
            __builtin_amdgcn_global_load_lds(AS1(ga), AS3(&As[j * 8]), 16, 0, 0);
            const bf16* gb = BT + (size_t)(n0 + row) * K + kt * 32 + kc * 8;
            __builtin_amdgcn_global_load_lds(AS1(gb), AS3(&Bs[j * 8]), 16, 0, 0);
        }
        asm volatile("s_waitcnt vmcnt(0)" ::: "memory");
        __syncthreads();

        s16x8 a[4], b[4];
#pragma unroll
        for (int i = 0; i < 4; i++) {
            int ra = wm * 64 + i * 16 + (lane & 15);
            a[i] = *(const s16x8*)&As[ra * 32 + (lane >> 4) * 8];
            int rb = wn * 64 + i * 16 + (lane & 15);
            b[i] = *(const s16x8*)&Bs[rb * 32 + (lane >> 4) * 8];
        }
#pragma unroll
        for (int i = 0; i < 4; i++)
#pragma unroll
            for (int j = 0; j < 4; j++)
                acc[i][j] = __builtin_amdgcn_mfma_f32_16x16x32_bf16(a[i], b[j], acc[i][j], 0, 0, 0);
    }

#pragma unroll
    for (int i = 0; i < 4; i++) {
        int gr0 = m0 + wm * 64 + i * 16 + ((lane >> 4) << 2);
#pragma unroll
        for (int j = 0; j < 4; j++) {
            int gc = n0 + wn * 64 + j * 16 + (lane & 15);
            float bv = (FLAGS & 1) ? bias[gc] : 0.f;
#pragma unroll
            for (int r = 0; r < 4; r++) {
                float v = acc[i][j][r] + bv;
                if (FLAGS & 2) v = gelu_f(v);
                if (FLAGS & 4) Cf[(size_t)(gr0 + r) * ldf + gc] = v;
                if (FLAGS & 8) Cb[(size_t)(gr0 + r) * ldb2 + gc] = __float2bfloat16(v);
            }
        }
    }
}

// ------------------------ transpose f32 -> bf16^T ---------------------------
// W: K x N (f32) -> WT: N x K (bf16)
__global__ __launch_bounds__(256) void transpose_bf16_kernel(const float* __restrict__ W,
                                                             bf16* __restrict__ WT, int K, int N) {
    __shared__ float t[32][33];
    int tx = threadIdx.x & 31, ty = threadIdx.x >> 5;
    int kb = blockIdx.y * 32, nb = blockIdx.x * 32;
#pragma unroll
    for (int i = 0; i < 4; i++)
        t[ty + 8 * i][tx] = W[(size_t)(kb + ty + 8 * i) * N + nb + tx];
    __syncthreads();
#pragma unroll
    for (int i = 0; i < 4; i++)
        WT[(size_t)(nb + ty + 8 * i) * K + kb + tx] = __float2bfloat16(t[tx][ty + 8 * i]);
}

// ------------------------------ f32 -> bf16 ---------------------------------
__global__ void conv_bf16_kernel(const float* __restrict__ src, bf16* __restrict__ dst) {
    size_t i = (size_t)blockIdx.x * 256 + threadIdx.x;
    f32x4 v = ((const f32x4*)src)[i];
    s16x4 o;
#pragma unroll
    for (int j = 0; j < 4; j++) {
        bf16 h = __float2bfloat16(v[j]);
        o[j] = *(short*)&h;
    }
    ((s16x4*)dst)[i] = o;
}

// ------------------------------ embedding ----------------------------------
__global__ void embed_kernel(const int* __restrict__ ids, const float* __restrict__ emb,
                             const float* __restrict__ pos, float* __restrict__ hF,
                             bf16* __restrict__ hB) {
    int t = blockIdx.x, tid = threadIdx.x;
    int id = ids[t];
    f32x4 v = ((const f32x4*)(emb + (size_t)id * H_))[tid];
    f32x4 q = ((const f32x4*)(pos + (size_t)t * H_))[tid];
    v = v + q;
    ((f32x4*)(hF + (size_t)t * H_))[tid] = v;
    s16x4 o;
#pragma unroll
    for (int j = 0; j < 4; j++) {
        bf16 h = __float2bfloat16(v[j]);
        o[j] = *(short*)&h;
    }
    ((s16x4*)(hB + (size_t)t * H_))[tid] = o;
}

// ------------------------------ LayerNorm ----------------------------------
__global__ __launch_bounds__(256) void ln_kernel(const float* __restrict__ x,
                                                 const float* __restrict__ res,
                                                 const float* __restrict__ g,
                                                 const float* __restrict__ b,
                                                 float* __restrict__ of, bf16* __restrict__ ob) {
    __shared__ float red[8];
    int row = blockIdx.x, tid = threadIdx.x, lane = tid & 63, wid = tid >> 6;
    const float* xr = x + (size_t)row * H_;
    float v[4];
#pragma unroll
    for (int j = 0; j < 4; j++) {
        int c = tid + 256 * j;
        v[j] = xr[c] + (res ? res[(size_t)row * H_ + c] : 0.f);
    }
    float s = v[0] + v[1] + v[2] + v[3];
#pragma unroll
    for (int o = 32; o; o >>= 1) s += __shfl_xor(s, o);
    if (!lane) red[wid] = s;
    __syncthreads();
    float mean = (red[0] + red[1] + red[2] + red[3]) * (1.f / H_);
    float q = 0.f;
#pragma unroll
    for (int j = 0; j < 4; j++) {
        float d = v[j] - mean;
        q += d * d;
    }
#pragma unroll
    for (int o = 32; o; o >>= 1) q += __shfl_xor(q, o);
    if (!lane) red[4 + wid] = q;
    __syncthreads();
    float var = (red[4] + red[5] + red[6] + red[7]) * (1.f / H_);
    float rstd = rsqrtf(var + 1e-5f);
#pragma unroll
    for (int j = 0; j < 4; j++) {
        int c = tid + 256 * j;
        float o2 = (v[j] - mean) * rstd * g[c] + b[c];
        if (of) of[(size_t)row * H_ + c] = o2;
        if (ob) ob[(size_t)row * H_ + c] = __float2bfloat16(o2);
    }
}

// --------------------------- key normalization ------------------------------
__global__ __launch_bounds__(256) void keynorm_kernel(float* __restrict__ keys) {
    int wid = threadIdx.x >> 6, lane = threadIdx.x & 63;
    int r = blockIdx.x * 4 + wid;
    float v[8], ss = 0.f;
#pragma unroll
    for (int j = 0; j < 8; j++) {
        v[j] = keys[(size_t)r * D_ + lane + 64 * j];
        ss += v[j] * v[j];
    }
#pragma unroll
    for (int o = 32; o; o >>= 1) ss += __shfl_xor(ss, o);
    float inv = 1.f / (sqrtf(ss) + 1e-6f);
#pragma unroll
    for (int j = 0; j < 8; j++) keys[(size_t)r * D_ + lane + 64 * j] = v[j] * inv;
}

// ------------------ attention over mem=[fast0;slow0] ------------------------
// One wave per query row: 64 lanes = 64 memory slots. scores -> softmax ->
// retrieved = (attn@mem)*keys. Writes retrieved f32 + bf16 into qr[:,1024:].
__global__ __launch_bounds__(256) void attn_kernel(const float* __restrict__ keys,
                                                   const float* __restrict__ fast0,
                                                   const float* __restrict__ slow0,
                                                   float* __restrict__ ret, bf16* __restrict__ qr) {
    __shared__ float klds[4][512];
    __shared__ float attn_s[4][64];
    int wid = threadIdx.x >> 6, lane = threadIdx.x & 63;
    const float* mrow = (lane < 32) ? (fast0 + (size_t)lane * D_) : (slow0 + (size_t)(lane - 32) * D_);
    for (int q = 0; q < 4; ++q) {
        int r = blockIdx.x * 16 + wid * 4 + q;
#pragma unroll
        for (int j = 0; j < 8; j++) klds[wid][lane + 64 * j] = keys[(size_t)r * D_ + lane + 64 * j];
        __syncthreads();
        float s = 0.f;
#pragma unroll 8
        for (int d = 0; d < 512; ++d) s = fmaf(klds[wid][d], mrow[d], s);
        s *= 0.044194173824159216f;  // 1/sqrt(512)
        float m = s;
#pragma unroll
        for (int o = 32; o; o >>= 1) m = fmaxf(m, __shfl_xor(m, o));
        float p = expf(s - m);
        float sum = p;
#pragma unroll
        for (int o = 32; o; o >>= 1) sum += __shfl_xor(sum, o);
        attn_s[wid][lane] = p / sum;
        __syncthreads();
        float rv[8];
#pragma unroll
        for (int j = 0; j < 8; j++) rv[j] = 0.f;
        for (int n2 = 0; n2 < 64; ++n2) {
            float a2 = attn_s[wid][n2];
            const float* m2 = (n2 < 32) ? (fast0 + (size_t)n2 * D_) : (slow0 + (size_t)(n2 - 32) * D_);
#pragma unroll
            for (int j = 0; j < 8; j++) rv[j] = fmaf(a2, m2[lane + 64 * j], rv[j]);
        }
#pragma unroll
        for (int j = 0; j < 8; j++) {
            float o = rv[j] * klds[wid][lane + 64 * j];
            ret[(size_t)r * D_ + lane + 64 * j] = o;
            qr[(size_t)r * 1536 + 1024 + lane + 64 * j] = __float2bfloat16(o);
        }
        __syncthreads();
    }
}

// ------------------------- scan coefficients --------------------------------
// coef[0..2047]=a_t, [2048..4095]=b_t, [4096]=c_ss, [4097]=c_fs
__global__ void coef_kernel(float* __restrict__ coef) {
    int t = blockIdx.x * 256 + threadIdx.x;
    int j0 = (t + 9) / 10;  // ceil(t/10); cons steps are t=10j, j=0..204
    float a = powf(0.9f, (float)(2047 - t + 205 - j0));
    float b = 0.f;
    for (int j = j0; j < 205; ++j)
        b += powf(0.9f, (float)(10 * j - t + j - j0)) * powf(0.99f, (float)(204 - j));
    b *= 0.1f;
    coef[t] = a;
    coef[2048 + t] = b;
    if (t == 0) {
        coef[4096] = powf(0.99f, 205.f);
        float cfs = 0.f;
        for (int j = 0; j < 205; ++j)
            cfs += powf(0.9f, (float)(11 * j + 1)) * powf(0.99f, (float)(204 - j));
        coef[4097] = 0.1f * cfs;
    }
}

// ------------------------------- gates --------------------------------------
// fast_gates = sigmoid([h|retrieved] @ gate_W[:, :32] + gate_b[:32])
// writes ga = a_t*g, gb = b_t*g  (pre-scaled for the scan GEMM)
__global__ __launch_bounds__(256) void gates_kernel(const float* __restrict__ hF,
                                                    const float* __restrict__ retF,
                                                    const float* __restrict__ gW,
                                                    const float* __restrict__ gB,
                                                    const float* __restrict__ coef,
                                                    float* __restrict__ ga, float* __restrict__ gb) {
    int r = blockIdx.x * 8 + (threadIdx.x >> 5);
    int n = threadIdx.x & 31;
    float acc = gB[n];
    const float* hr = hF + (size_t)r * H_;
#pragma unroll 8
    for (int k = 0; k < H_; ++k) acc = fmaf(hr[k], gW[k * 64 + n], acc);
    const float* rr = retF + (size_t)r * D_;
#pragma unroll 8
    for (int k = 0; k < D_; ++k) acc = fmaf(rr[k], gW[(H_ + k) * 64 + n], acc);
    float g = 1.f / (1.f + expf(-acc));
    ga[r * 32 + n] = g * coef[r];
    gb[r * 32 + n] = g * coef[2048 + r];
}

// ------------------------------- scan GEMMs ---------------------------------
// fast[m,d] = sum_t ga[t,m]*items[t,d]
// slow[m,d] = sum_t gb[t,m]*items[t,d] + c_ss*slow0 + c_fs*fast0
__global__ __launch_bounds__(256) void scan_kernel(const float* __restrict__ items,
                                                   const float* __restrict__ ga,
                                                   const float* __restrict__ gb,
                                                   const float* __restrict__ coef,
                                                   const float* __restrict__ fast0,
                                                   const float* __restrict__ slow0,
                                                   float* __restrict__ fastO,
                                                   float* __restrict__ slowO) {
    int tid = threadIdx.x;
    int d = (blockIdx.x & 7) * 64 + (tid & 63);
    int m0 = (blockIdx.x >> 3) * 16 + (tid >> 6) * 4;
    float aF[4] = {0.f, 0.f, 0.f, 0.f}, aS[4] = {0.f, 0.f, 0.f, 0.f};
    for (int t = 0; t < 2048; ++t) {
        float it = items[(size_t)t * D_ + d];
#pragma unroll
        for (int j = 0; j < 4; j++) {
            aF[j] = fmaf(ga[t * 32 + m0 + j], it, aF[j]);
            aS[j] = fmaf(gb[t * 32 + m0 + j], it, aS[j]);
        }
    }
    float css = coef[4096], cfs = coef[4097];
#pragma unroll
    for (int j = 0; j < 4; j++) {
        int m = m0 + j;
        fastO[m * D_ + d] = aF[j];
        slowO[m * D_ + d] = aS[j] + css * slow0[m * D_ + d] + cfs * fast0[m * D_ + d];
    }
}

// ------------------------------- host side ----------------------------------
static inline void gemm(hipStream_t st, const bf16* A, const bf16* BT, const float* bias,
                        float* Cf, int ldf, bf16* Cb, int ldb2, int M, int N, int K, int flags) {
    dim3 g(N / 128, M / 128), b(256);
    switch (flags) {
        case 4:  gemm_nt<4><<<g, b, 0, st>>>(A, BT, bias, Cf, ldf, Cb, ldb2, K); break;
        case 5:  gemm_nt<5><<<g, b, 0, st>>>(A, BT, bias, Cf, ldf, Cb, ldb2, K); break;
        case 9:  gemm_nt<9><<<g, b, 0, st>>>(A, BT, bias, Cf, ldf, Cb, ldb2, K); break;
        case 11: gemm_nt<11><<<g, b, 0, st>>>(A, BT, bias, Cf, ldf, Cb, ldb2, K); break;
        case 13: gemm_nt<13><<<g, b, 0, st>>>(A, BT, bias, Cf, ldf, Cb, ldb2, K); break;
    }
}

static inline void transp(hipStream_t st, const float* W, bf16* WT, int K, int N) {
    transpose_bf16_kernel<<<dim3(N / 32, K / 32), 256, 0, st>>>(W, WT, K, N);
}

extern "C" void kernel_launch(void* const* d_in, const int* in_sizes, int n_in,
                              void* d_out, int out_size, void* d_ws, size_t ws_size,
                              hipStream_t stream) {
    const int* ids = (const int*)d_in[0];
    const float* fastS = (const float*)d_in[1];
    const float* slowS = (const float*)d_in[2];
    const float* emb = (const float*)d_in[3];
    const float* pos = (const float*)d_in[4];
    const float* W_item = (const float*)d_in[5];
    const float* b_item = (const float*)d_in[6];
    const float* W_q = (const float*)d_in[7];
    const float* b_q = (const float*)d_in[8];
    const float* rh_W1 = (const float*)d_in[9];
    const float* rh_b1 = (const float*)d_in[10];
    const float* rh_W2 = (const float*)d_in[11];
    const float* rh_b2 = (const float*)d_in[12];
    const float* gate_W = (const float*)d_in[13];
    const float* gate_b = (const float*)d_in[14];
    const float* W_out = (const float*)d_in[15];
    const float* b_out = (const float*)d_in[16];
    const float* ln1_g = (const float*)d_in[17];
    const float* ln1_b = (const float*)d_in[18];
    const float* ffn_W1 = (const float*)d_in[19];
    const float* ffn_b1 = (const float*)d_in[20];
    const float* ffn_W2 = (const float*)d_in[21];
    const float* ffn_b2 = (const float*)d_in[22];
    const float* ln2_g = (const float*)d_in[23];
    const float* ln2_b = (const float*)d_in[24];
    const float* fln_g = (const float*)d_in[25];
    const float* fln_b = (const float*)d_in[26];
    float* outP = (float*)d_out;

    size_t off = 0;
    char* base = (char*)d_ws;
    auto alloc = [&](size_t n) -> char* {
        char* p = base + off;
        off += (n + 255) & ~(size_t)255;
        return p;
    };
    bf16* wItemT = (bf16*)alloc((size_t)Lc * D_ * H_ * 2);
    bf16* wQT = (bf16*)alloc((size_t)Lc * H_ * H_ * 2);
    bf16* rh1T = (bf16*)alloc((size_t)Lc * (2 * D_) * D_ * 2);
    bf16* rh2T = (bf16*)alloc((size_t)Lc * D_ * (2 * D_) * 2);
    bf16* wOutT = (bf16*)alloc((size_t)Lc * H_ * 1536 * 2);
    bf16* f1T = (bf16*)alloc((size_t)Lc * I_ * H_ * 2);
    bf16* f2T = (bf16*)alloc((size_t)Lc * H_ * I_ * 2);
    bf16* embB = (bf16*)alloc((size_t)V_ * H_ * 2);
    float* hF = (float*)alloc((size_t)S_ * H_ * 4);
    bf16* hB = (bf16*)alloc((size_t)S_ * H_ * 2);
    float* itemsF = (float*)alloc((size_t)S_ * D_ * 4);
    bf16* itemsB = (bf16*)alloc((size_t)S_ * D_ * 2);
    bf16* qrB = (bf16*)alloc((size_t)S_ * 1536 * 2);
    bf16* k1B = (bf16*)alloc((size_t)S_ * (2 * D_) * 2);
    float* keysF = (float*)alloc((size_t)S_ * D_ * 4);
    float* retF = (float*)alloc((size_t)S_ * D_ * 4);
    float* outF = (float*)alloc((size_t)S_ * H_ * 4);  // also reused for ffn2
    bf16* ffn1B = (bf16*)alloc((size_t)S_ * I_ * 2);
    float* gaF = (float*)alloc((size_t)S_ * SLn * 4);
    float* gbF = (float*)alloc((size_t)S_ * SLn * 4);
    float* coefF = (float*)alloc(4200 * 4);

    coef_kernel<<<8, 256, 0, stream>>>(coefF);
    for (int l = 0; l < Lc; ++l) {
        transp(stream, W_item + (size_t)l * H_ * D_, wItemT + (size_t)l * D_ * H_, H_, D_);
        transp(stream, W_q + (size_t)l * H_ * H_, wQT + (size_t)l * H_ * H_, H_, H_);
        transp(stream, rh_W1 + (size_t)l * D_ * 2 * D_, rh1T + (size_t)l * 2 * D_ * D_, D_, 2 * D_);
        transp(stream, rh_W2 + (size_t)l * 2 * D_ * D_, rh2T + (size_t)l * D_ * 2 * D_, 2 * D_, D_);
        transp(stream, W_out + (size_t)l * 1536 * H_, wOutT + (size_t)l * H_ * 1536, 1536, H_);
        transp(stream, ffn_W1 + (size_t)l * H_ * I_, f1T + (size_t)l * I_ * H_, H_, I_);
        transp(stream, ffn_W2 + (size_t)l * I_ * H_, f2T + (size_t)l * H_ * I_, I_, H_);
    }
    conv_bf16_kernel<<<(int)((size_t)V_ * H_ / 4 / 256), 256, 0, stream>>>(emb, embB);
    embed_kernel<<<S_, 256, 0, stream>>>(ids, emb, pos, hF, hB);

    for (int l = 0; l < Lc; ++l) {
        const float* fast0 = fastS + (size_t)l * SLn * D_;
        const float* slow0 = slowS + (size_t)l * SLn * D_;
        // items (f32+bf16), query (bf16 into qr[:, :1024])
        gemm(stream, hB, wItemT + (size_t)l * D_ * H_, b_item + l * D_, itemsF, D_, itemsB, D_,
             S_, D_, H_, 13);
        gemm(stream, hB, wQT + (size_t)l * H_ * H_, b_q + l * H_, nullptr, 0, qrB, 1536,
             S_, H_, H_, 9);
        // k1 = gelu(items@rh_W1+b), keys_raw = k1@rh_W2+b
        gemm(stream, itemsB, rh1T + (size_t)l * 2 * D_ * D_, rh_b1 + l * 2 * D_, nullptr, 0, k1B,
             2 * D_, S_, 2 * D_, D_, 11);
        gemm(stream, k1B, rh2T + (size_t)l * D_ * 2 * D_, rh_b2 + l * D_, keysF, D_, nullptr, 0,
             S_, D_, 2 * D_, 5);
        keynorm_kernel<<<S_ / 4, 256, 0, stream>>>(keysF);
        attn_kernel<<<S_ / 16, 256, 0, stream>>>(keysF, fast0, slow0, retF, qrB);
        gates_kernel<<<S_ / 8, 256, 0, stream>>>(hF, retF, gate_W + (size_t)l * 1536 * 64,
                                                 gate_b + l * 64, coefF, gaF, gbF);
        scan_kernel<<<16, 256, 0, stream>>>(itemsF, gaF, gbF, coefF, fast0, slow0,
                                            outP + LOGITS_N + (size_t)l * SLn * D_,
                                            outP + LOGITS_N + (size_t)Lc * SLn * D_ + (size_t)l * SLn * D_);
        // out = [query|retrieved] @ W_out + b
        gemm(stream, qrB, wOutT + (size_t)l * H_ * 1536, b_out + l * H_, outF, H_, nullptr, 0,
             S_, H_, 1536, 5);
        ln_kernel<<<S_, 256, 0, stream>>>(hF, outF, ln1_g + l * H_, ln1_b + l * H_, hF, hB);
        // FFN
        gemm(stream, hB, f1T + (size_t)l * I_ * H_, ffn_b1 + l * I_, nullptr, 0, ffn1B, I_,
             S_, I_, H_, 11);
        gemm(stream, ffn1B, f2T + (size_t)l * H_ * I_, ffn_b2 + l * H_, outF, H_, nullptr, 0,
             S_, H_, I_, 5);
        ln_kernel<<<S_, 256, 0, stream>>>(hF, outF, ln2_g + l * H_, ln2_b + l * H_, hF, hB);
    }
    // final LN (bf16 only) + logits
    ln_kernel<<<S_, 256, 0, stream>>>(hF, nullptr, fln_g, fln_b, nullptr, hB);
    gemm(stream, hB, embB, nullptr, outP, V_, nullptr, 0, S_, V_, H_, 4);
}

// Round 2
// 1292.324 us; speedup vs baseline: 1.3776x; 1.3776x over previous
//
#include <hip/hip_runtime.h>
#include <hip/hip_bf16.h>
#include <stdint.h>

typedef __hip_bfloat16 bf16;
typedef float f32x4 __attribute__((ext_vector_type(4)));
typedef short s16x8 __attribute__((ext_vector_type(8)));
typedef short s16x4 __attribute__((ext_vector_type(4)));

#define DEV __device__ __forceinline__

static constexpr int S_ = 2048, H_ = 1024, D_ = 512, I_ = 4096, V_ = 32000;
static constexpr int SLn = 32, Lc = 2;
static constexpr size_t LOGITS_N = (size_t)S_ * V_;

DEV float gelu_f(float x) {
    float x3 = x * x * x;
    return 0.5f * x * (1.f + tanhf(0.7978845608028654f * (x + 0.044715f * x3)));
}

#define AS1(p) ((const __attribute__((address_space(1))) void*)(uintptr_t)(p))
#define AS3(p) ((__attribute__((address_space(3))) void*)(uint32_t)(uintptr_t)(p))

// ------------------------------ GEMM (NT) ----------------------------------
// C[M,N] = A[M,K] @ BT[N,K]^T (+bias,+gelu). 2-phase double-buffered staging,
// XCD-chunked swizzle with m-fastest ordering (B-tile L2 reuse).
// FLAGS: 1=bias, 2=gelu, 4=store f32, 8=store bf16
template <int BM, int BN, int FLAGS>
__global__ __launch_bounds__(256) void gemm_nt(const bf16* __restrict__ A,
                                               const bf16* __restrict__ BT,
                                               const float* __restrict__ bias,
                                               float* __restrict__ Cf, int ldf,
                                               bf16* __restrict__ Cb, int ldb2,
                                               int K, int Mt, int Nt) {
    constexpr int FM = BM / 32, FN = BN / 32;
    constexpr int CA = BM / 64, CB = BN / 64;
    __shared__ short As[2 * BM * 32];
    __shared__ short Bs[2 * BN * 32];
    const int tid = threadIdx.x;
    const int lane = tid & 63;
    const int wm = (tid >> 6) >> 1, wn = (tid >> 6) & 1;

    int nwg = Mt * Nt;
    int bid = blockIdx.x, wgid = bid;
    if ((nwg & 7) == 0) {  // bijective XCD-chunked swizzle
        int cpx = nwg >> 3;
        wgid = (bid & 7) * cpx + (bid >> 3);
    }
    const int m0 = (wgid % Mt) * BM, n0 = (wgid / Mt) * BN;

    f32x4 acc[FM][FN];
#pragma unroll
    for (int i = 0; i < FM; i++)
#pragma unroll
        for (int j = 0; j < FN; j++)
#pragma unroll
            for (int r = 0; r < 4; r++) acc[i][j][r] = 0.f;

    auto stage = [&](int kt, int buf) {
        short* as = As + buf * (BM * 32);
        short* bs = Bs + buf * (BN * 32);
#pragma unroll
        for (int h = 0; h < CA; ++h) {
            int j = tid + h * 256;
            int row = j >> 2, kc = j & 3;
            const bf16* ga = A + (size_t)(m0 + row) * K + kt * 32 + kc * 8;
            __builtin_amdgcn_global_load_lds(AS1(ga), AS3(&as[j * 8]), 16, 0, 0);
        }
#pragma unroll
        for (int h = 0; h < CB; ++h) {
            int j = tid + h * 256;
            int row = j >> 2, kc = j & 3;
            const bf16* gb = BT + (size_t)(n0 + row) * K + kt * 32 + kc * 8;
            __builtin_amdgcn_global_load_lds(AS1(gb), AS3(&bs[j * 8]), 16, 0, 0);
        }
    };
    auto compute = [&](int buf) {
        const short* as = As + buf * (BM * 32);
        const short* bs = Bs + buf * (BN * 32);
        s16x8 a[FM], b[FN];
#pragma unroll
        for (int i = 0; i < FM; i++)
            a[i] = *(const s16x8*)&as[(wm * (BM / 2) + i * 16 + (lane & 15)) * 32 + (lane >> 4) * 8];
#pragma unroll
        for (int j = 0; j < FN; j++)
            b[j] = *(const s16x8*)&bs[(wn * (BN / 2) + j * 16 + (lane & 15)) * 32 + (lane >> 4) * 8];
#pragma unroll
        for (int i = 0; i < FM; i++)
#pragma unroll
            for (int j = 0; j < FN; j++)
                acc[i][j] = __builtin_amdgcn_mfma_f32_16x16x32_bf16(a[i], b[j], acc[i][j], 0, 0, 0);
    };

    const int nk = K >> 5;
    stage(0, 0);
    asm volatile("s_waitcnt vmcnt(0)" ::: "memory");
    __syncthreads();
    int cur = 0;
    for (int kt = 0; kt < nk - 1; ++kt) {
        stage(kt + 1, cur ^ 1);  // prefetch next tile; latency hides under compute
        compute(cur);
        asm volatile("s_waitcnt vmcnt(0)" ::: "memory");
        __syncthreads();
        cur ^= 1;
    }
    compute(cur);

#pragma unroll
    for (int i = 0; i < FM; i++) {
        int gr0 = m0 + wm * (BM / 2) + i * 16 + ((lane >> 4) << 2);
#pragma unroll
        for (int j = 0; j < FN; j++) {
            int gc = n0 + wn * (BN / 2) + j * 16 + (lane & 15);
            float bv = (FLAGS & 1) ? bias[gc] : 0.f;
#pragma unroll
            for (int r = 0; r < 4; r++) {
                float v = acc[i][j][r] + bv;
                if (FLAGS & 2) v = gelu_f(v);
                if (FLAGS & 4) Cf[(size_t)(gr0 + r) * ldf + gc] = v;
                if (FLAGS & 8) Cb[(size_t)(gr0 + r) * ldb2 + gc] = __float2bfloat16(v);
            }
        }
    }
}

// ------------------------ transpose f32 -> bf16^T ---------------------------
__global__ __launch_bounds__(256) void transpose_bf16_kernel(const float* __restrict__ W,
                                                             bf16* __restrict__ WT, int K, int N) {
    __shared__ float t[32][33];
    int tx = threadIdx.x & 31, ty = threadIdx.x >> 5;
    int kb = blockIdx.y * 32, nb = blockIdx.x * 32;
#pragma unroll
    for (int i = 0; i < 4; i++)
        t[ty + 8 * i][tx] = W[(size_t)(kb + ty + 8 * i) * N + nb + tx];
    __syncthreads();
#pragma unroll
    for (int i = 0; i < 4; i++)
        WT[(size_t)(nb + ty + 8 * i) * K + kb + tx] = __float2bfloat16(t[tx][ty + 8 * i]);
}

// ------------------------------ f32 -> bf16 ---------------------------------
__global__ void conv_bf16_kernel(const float* __restrict__ src, bf16* __restrict__ dst) {
    size_t i = (size_t)blockIdx.x * 256 + threadIdx.x;
    f32x4 v = ((const f32x4*)src)[i];
    s16x4 o;
#pragma unroll
    for (int j = 0; j < 4; j++) {
        bf16 h = __float2bfloat16(v[j]);
        o[j] = *(short*)&h;
    }
    ((s16x4*)dst)[i] = o;
}

// ------------------------------ embedding ----------------------------------
__global__ void embed_kernel(const int* __restrict__ ids, const float* __restrict__ emb,
                             const float* __restrict__ pos, float* __restrict__ hF,
                             bf16* __restrict__ hB) {
    int t = blockIdx.x, tid = threadIdx.x;
    int id = ids[t];
    f32x4 v = ((const f32x4*)(emb + (size_t)id * H_))[tid];
    f32x4 q = ((const f32x4*)(pos + (size_t)t * H_))[tid];
    v = v + q;
    ((f32x4*)(hF + (size_t)t * H_))[tid] = v;
    s16x4 o;
#pragma unroll
    for (int j = 0; j < 4; j++) {
        bf16 h = __float2bfloat16(v[j]);
        o[j] = *(short*)&h;
    }
    ((s16x4*)(hB + (size_t)t * H_))[tid] = o;
}

// ------------------------------ LayerNorm ----------------------------------
__global__ __launch_bounds__(256) void ln_kernel(const float* __restrict__ x,
                                                 const float* __restrict__ res,
                                                 const float* __restrict__ g,
                                                 const float* __restrict__ b,
                                                 float* __restrict__ of, bf16* __restrict__ ob) {
    __shared__ float red[8];
    int row = blockIdx.x, tid = threadIdx.x, lane = tid & 63, wid = tid >> 6;
    const float* xr = x + (size_t)row * H_;
    float v[4];
#pragma unroll
    for (int j = 0; j < 4; j++) {
        int c = tid + 256 * j;
        v[j] = xr[c] + (res ? res[(size_t)row * H_ + c] : 0.f);
    }
    float s = v[0] + v[1] + v[2] + v[3];
#pragma unroll
    for (int o = 32; o; o >>= 1) s += __shfl_xor(s, o);
    if (!lane) red[wid] = s;
    __syncthreads();
    float mean = (red[0] + red[1] + red[2] + red[3]) * (1.f / H_);
    float q = 0.f;
#pragma unroll
    for (int j = 0; j < 4; j++) {
        float d = v[j] - mean;
        q += d * d;
    }
#pragma unroll
    for (int o = 32; o; o >>= 1) q += __shfl_xor(q, o);
    if (!lane) red[4 + wid] = q;
    __syncthreads();
    float var = (red[4] + red[5] + red[6] + red[7]) * (1.f / H_);
    float rstd = rsqrtf(var + 1e-5f);
#pragma unroll
    for (int j = 0; j < 4; j++) {
        int c = tid + 256 * j;
        float o2 = (v[j] - mean) * rstd * g[c] + b[c];
        if (of) of[(size_t)row * H_ + c] = o2;
        if (ob) ob[(size_t)row * H_ + c] = __float2bfloat16(o2);
    }
}

// --------------------- mem transpose for attn scores ------------------------
// memT[d][n] = (n<32 ? fast0[n][d] : slow0[n-32][d]); 512x64 f32
__global__ void memt_kernel(const float* __restrict__ fast0, const float* __restrict__ slow0,
                            float* __restrict__ memT) {
    int idx = blockIdx.x * 256 + threadIdx.x;  // 32768 total
    int d = idx >> 6, n = idx & 63;
    const float* m = (n < 32) ? fast0 + (size_t)n * D_ : slow0 + (size_t)(n - 32) * D_;
    memT[idx] = m[d];
}

// ---------------- attention (fused keynorm) over 64 memory slots ------------
__global__ __launch_bounds__(256) void attn_kernel(const float* __restrict__ keys,
                                                   const float* __restrict__ memT,
                                                   const float* __restrict__ fast0,
                                                   const float* __restrict__ slow0,
                                                   float* __restrict__ ret, bf16* __restrict__ qr) {
    __shared__ float klds[4][512];
    int wid = threadIdx.x >> 6, lane = threadIdx.x & 63;
    for (int q = 0; q < 4; ++q) {
        int r = blockIdx.x * 16 + wid * 4 + q;
        // load + normalize keys row (fused keynorm)
        float kv[8], ss = 0.f;
#pragma unroll
        for (int j = 0; j < 8; j++) {
            kv[j] = keys[(size_t)r * D_ + lane + 64 * j];
            ss += kv[j] * kv[j];
        }
#pragma unroll
        for (int o = 32; o; o >>= 1) ss += __shfl_xor(ss, o);
        float inv = 1.f / (sqrtf(ss) + 1e-6f);
#pragma unroll
        for (int j = 0; j < 8; j++) {
            kv[j] *= inv;
            klds[wid][lane + 64 * j] = kv[j];
        }
        // scores: lane = memory slot; memT loads coalesced
        float s0 = 0.f, s1 = 0.f, s2 = 0.f, s3 = 0.f;
#pragma unroll 8
        for (int d = 0; d < 512; d += 4) {
            s0 = fmaf(klds[wid][d + 0], memT[(d + 0) * 64 + lane], s0);
            s1 = fmaf(klds[wid][d + 1], memT[(d + 1) * 64 + lane], s1);
            s2 = fmaf(klds[wid][d + 2], memT[(d + 2) * 64 + lane], s2);
            s3 = fmaf(klds[wid][d + 3], memT[(d + 3) * 64 + lane], s3);
        }
        float s = (s0 + s1 + s2 + s3) * 0.044194173824159216f;  // 1/sqrt(512)
        float m = s;
#pragma unroll
        for (int o = 32; o; o >>= 1) m = fmaxf(m, __shfl_xor(m, o));
        float p = expf(s - m);
        float sum = p;
#pragma unroll
        for (int o = 32; o; o >>= 1) sum += __shfl_xor(sum, o);
        float pn = p / sum;
        // retrieved = (attn @ mem) * keys
        float rv[8];
#pragma unroll
        for (int j = 0; j < 8; j++) rv[j] = 0.f;
        for (int n2 = 0; n2 < 64; ++n2) {
            float a2 = __shfl(pn, n2);
            const float* m2 = (n2 < 32) ? (fast0 + (size_t)n2 * D_) : (slow0 + (size_t)(n2 - 32) * D_);
#pragma unroll
            for (int j = 0; j < 8; j++) rv[j] = fmaf(a2, m2[lane + 64 * j], rv[j]);
        }
#pragma unroll
        for (int j = 0; j < 8; j++) {
            float o = rv[j] * kv[j];
            ret[(size_t)r * D_ + lane + 64 * j] = o;
            qr[(size_t)r * 1536 + 1024 + lane + 64 * j] = __float2bfloat16(o);
        }
    }
}

// ------------------------- scan coefficients --------------------------------
__global__ void coef_kernel(float* __restrict__ coef) {
    int t = blockIdx.x * 256 + threadIdx.x;
    int j0 = (t + 9) / 10;
    float a = powf(0.9f, (float)(2047 - t + 205 - j0));
    float b = 0.f;
    for (int j = j0; j < 205; ++j)
        b += powf(0.9f, (float)(10 * j - t + j - j0)) * powf(0.99f, (float)(204 - j));
    b *= 0.1f;
    coef[t] = a;
    coef[2048 + t] = b;
    if (t == 0) {
        coef[4096] = powf(0.99f, 205.f);
        float cfs = 0.f;
        for (int j = 0; j < 205; ++j)
            cfs += powf(0.9f, (float)(11 * j + 1)) * powf(0.99f, (float)(204 - j));
        coef[4097] = 0.1f * cfs;
    }
}

// ------------------------------- gates --------------------------------------
__global__ __launch_bounds__(256) void gates_kernel(const float* __restrict__ hF,
                                                    const float* __restrict__ retF,
                                                    const float* __restrict__ gW,
                                                    const float* __restrict__ gB,
                                                    const float* __restrict__ coef,
                                                    float* __restrict__ ga, float* __restrict__ gb) {
    int r = blockIdx.x * 8 + (threadIdx.x >> 5);
    int n = threadIdx.x & 31;
    float acc = gB[n];
    const float* hr = hF + (size_t)r * H_;
#pragma unroll 8
    for (int k = 0; k < H_; ++k) acc = fmaf(hr[k], gW[k * 64 + n], acc);
    const float* rr = retF + (size_t)r * D_;
#pragma unroll 8
    for (int k = 0; k < D_; ++k) acc = fmaf(rr[k], gW[(H_ + k) * 64 + n], acc);
    float g = 1.f / (1.f + expf(-acc));
    ga[r * 32 + n] = g * coef[r];
    gb[r * 32 + n] = g * coef[2048 + r];
}

// ------------------------- scan: split-T partial GEMMs ----------------------
// grid 128 = dg(8) x mg(2) x tc(8); partial[tc][32][512]
__global__ __launch_bounds__(256) void scan_part_kernel(const float* __restrict__ items,
                                                        const float* __restrict__ ga,
                                                        const float* __restrict__ gb,
                                                        float* __restrict__ pF,
                                                        float* __restrict__ pS) {
    int tid = threadIdx.x;
    int d = (blockIdx.x & 7) * 64 + (tid & 63);
    int mg = (blockIdx.x >> 3) & 1;
    int tc = blockIdx.x >> 4;
    int m0 = mg * 16 + (tid >> 6) * 4;
    float aF[4] = {0.f, 0.f, 0.f, 0.f}, aS[4] = {0.f, 0.f, 0.f, 0.f};
    for (int t = tc * 256; t < tc * 256 + 256; ++t) {
        float it = items[(size_t)t * D_ + d];
#pragma unroll
        for (int j = 0; j < 4; j++) {
            aF[j] = fmaf(ga[t * 32 + m0 + j], it, aF[j]);
            aS[j] = fmaf(gb[t * 32 + m0 + j], it, aS[j]);
        }
    }
#pragma unroll
    for (int j = 0; j < 4; j++) {
        pF[((size_t)tc * 32 + m0 + j) * D_ + d] = aF[j];
        pS[((size_t)tc * 32 + m0 + j) * D_ + d] = aS[j];
    }
}

__global__ __launch_bounds__(256) void scan_reduce_kernel(const float* __restrict__ pF,
                                                          const float* __restrict__ pS,
                                                          const float* __restrict__ coef,
                                                          const float* __restrict__ fast0,
                                                          const float* __restrict__ slow0,
                                                          float* __restrict__ fastO,
                                                          float* __restrict__ slowO) {
    int i = blockIdx.x * 256 + threadIdx.x;  // 32*512 = 16384
    float f = 0.f, s = 0.f;
#pragma unroll
    for (int c = 0; c < 8; c++) {
        f += pF[(size_t)c * 32 * D_ + i];
        s += pS[(size_t)c * 32 * D_ + i];
    }
    fastO[i] = f;
    slowO[i] = s + coef[4096] * slow0[i] + coef[4097] * fast0[i];
}

// ------------------------------- host side ----------------------------------
static inline void gemm(hipStream_t st, int BM, int BN, const bf16* A, const bf16* BT,
                        const float* bias, float* Cf, int ldf, bf16* Cb, int ldb2,
                        int M, int N, int K, int flags) {
    int Mt = M / BM, Nt = N / BN;
    dim3 g(Mt * Nt), b(256);
#define GCASE(bm, bn, fl)                                                              \
    if (BM == bm && BN == bn && flags == fl) {                                         \
        gemm_nt<bm, bn, fl><<<g, b, 0, st>>>(A, BT, bias, Cf, ldf, Cb, ldb2, K, Mt, Nt); \
        return;                                                                        \
    }
    GCASE(128, 128, 4)
    GCASE(128, 128, 11)
    GCASE(128, 64, 9)
    GCASE(128, 64, 11)
    GCASE(128, 64, 5)
    GCASE(64, 64, 13)
    GCASE(64, 64, 5)
#undef GCASE
}

static inline void transp(hipStream_t st, const float* W, bf16* WT, int K, int N) {
    transpose_bf16_kernel<<<dim3(N / 32, K / 32), 256, 0, st>>>(W, WT, K, N);
}

extern "C" void kernel_launch(void* const* d_in, const int* in_sizes, int n_in,
                              void* d_out, int out_size, void* d_ws, size_t ws_size,
                              hipStream_t stream) {
    const int* ids = (const int*)d_in[0];
    const float* fastS = (const float*)d_in[1];
    const float* slowS = (const float*)d_in[2];
    const float* emb = (const float*)d_in[3];
    const float* pos = (const float*)d_in[4];
    const float* W_item = (const float*)d_in[5];
    const float* b_item = (const float*)d_in[6];
    const float* W_q = (const float*)d_in[7];
    const float* b_q = (const float*)d_in[8];
    const float* rh_W1 = (const float*)d_in[9];
    const float* rh_b1 = (const float*)d_in[10];
    const float* rh_W2 = (const float*)d_in[11];
    const float* rh_b2 = (const float*)d_in[12];
    const float* gate_W = (const float*)d_in[13];
    const float* gate_b = (const float*)d_in[14];
    const float* W_out = (const float*)d_in[15];
    const float* b_out = (const float*)d_in[16];
    const float* ln1_g = (const float*)d_in[17];
    const float* ln1_b = (const float*)d_in[18];
    const float* ffn_W1 = (const float*)d_in[19];
    const float* ffn_b1 = (const float*)d_in[20];
    const float* ffn_W2 = (const float*)d_in[21];
    const float* ffn_b2 = (const float*)d_in[22];
    const float* ln2_g = (const float*)d_in[23];
    const float* ln2_b = (const float*)d_in[24];
    const float* fln_g = (const float*)d_in[25];
    const float* fln_b = (const float*)d_in[26];
    float* outP = (float*)d_out;

    size_t off = 0;
    char* base = (char*)d_ws;
    auto alloc = [&](size_t n) -> char* {
        char* p = base + off;
        off += (n + 255) & ~(size_t)255;
        return p;
    };
    bf16* wItemT = (bf16*)alloc((size_t)Lc * D_ * H_ * 2);
    bf16* wQT = (bf16*)alloc((size_t)Lc * H_ * H_ * 2);
    bf16* rh1T = (bf16*)alloc((size_t)Lc * (2 * D_) * D_ * 2);
    bf16* rh2T = (bf16*)alloc((size_t)Lc * D_ * (2 * D_) * 2);
    bf16* wOutT = (bf16*)alloc((size_t)Lc * H_ * 1536 * 2);
    bf16* f1T = (bf16*)alloc((size_t)Lc * I_ * H_ * 2);
    bf16* f2T = (bf16*)alloc((size_t)Lc * H_ * I_ * 2);
    bf16* embB = (bf16*)alloc((size_t)V_ * H_ * 2);
    float* hF = (float*)alloc((size_t)S_ * H_ * 4);
    bf16* hB = (bf16*)alloc((size_t)S_ * H_ * 2);
    float* itemsF = (float*)alloc((size_t)S_ * D_ * 4);
    bf16* itemsB = (bf16*)alloc((size_t)S_ * D_ * 2);
    bf16* qrB = (bf16*)alloc((size_t)S_ * 1536 * 2);
    bf16* k1B = (bf16*)alloc((size_t)S_ * (2 * D_) * 2);
    float* keysF = (float*)alloc((size_t)S_ * D_ * 4);
    float* retF = (float*)alloc((size_t)S_ * D_ * 4);
    float* outF = (float*)alloc((size_t)S_ * H_ * 4);
    bf16* ffn1B = (bf16*)alloc((size_t)S_ * I_ * 2);
    float* gaF = (float*)alloc((size_t)S_ * SLn * 4);
    float* gbF = (float*)alloc((size_t)S_ * SLn * 4);
    float* coefF = (float*)alloc(4200 * 4);
    float* memT = (float*)alloc((size_t)D_ * 64 * 4);
    float* pF = (float*)alloc((size_t)8 * SLn * D_ * 4);
    float* pS = (float*)alloc((size_t)8 * SLn * D_ * 4);

    coef_kernel<<<8, 256, 0, stream>>>(coefF);
    for (int l = 0; l < Lc; ++l) {
        transp(stream, W_item + (size_t)l * H_ * D_, wItemT + (size_t)l * D_ * H_, H_, D_);
        transp(stream, W_q + (size_t)l * H_ * H_, wQT + (size_t)l * H_ * H_, H_, H_);
        transp(stream, rh_W1 + (size_t)l * D_ * 2 * D_, rh1T + (size_t)l * 2 * D_ * D_, D_, 2 * D_);
        transp(stream, rh_W2 + (size_t)l * 2 * D_ * D_, rh2T + (size_t)l * D_ * 2 * D_, 2 * D_, D_);
        transp(stream, W_out + (size_t)l * 1536 * H_, wOutT + (size_t)l * H_ * 1536, 1536, H_);
        transp(stream, ffn_W1 + (size_t)l * H_ * I_, f1T + (size_t)l * I_ * H_, H_, I_);
        transp(stream, ffn_W2 + (size_t)l * I_ * H_, f2T + (size_t)l * H_ * I_, I_, H_);
    }
    conv_bf16_kernel<<<(int)((size_t)V_ * H_ / 4 / 256), 256, 0, stream>>>(emb, embB);
    embed_kernel<<<S_, 256, 0, stream>>>(ids, emb, pos, hF, hB);

    for (int l = 0; l < Lc; ++l) {
        const float* fast0 = fastS + (size_t)l * SLn * D_;
        const float* slow0 = slowS + (size_t)l * SLn * D_;
        gemm(stream, 64, 64, hB, wItemT + (size_t)l * D_ * H_, b_item + l * D_, itemsF, D_,
             itemsB, D_, S_, D_, H_, 13);
        gemm(stream, 128, 64, hB, wQT + (size_t)l * H_ * H_, b_q + l * H_, nullptr, 0, qrB, 1536,
             S_, H_, H_, 9);
        gemm(stream, 128, 64, itemsB, rh1T + (size_t)l * 2 * D_ * D_, rh_b1 + l * 2 * D_, nullptr,
             0, k1B, 2 * D_, S_, 2 * D_, D_, 11);
        gemm(stream, 64, 64, k1B, rh2T + (size_t)l * D_ * 2 * D_, rh_b2 + l * D_, keysF, D_,
             nullptr, 0, S_, D_, 2 * D_, 5);
        memt_kernel<<<128, 256, 0, stream>>>(fast0, slow0, memT);
        attn_kernel<<<S_ / 16, 256, 0, stream>>>(keysF, memT, fast0, slow0, retF, qrB);
        gates_kernel<<<S_ / 8, 256, 0, stream>>>(hF, retF, gate_W + (size_t)l * 1536 * 64,
                                                 gate_b + l * 64, coefF, gaF, gbF);
        scan_part_kernel<<<128, 256, 0, stream>>>(itemsF, gaF, gbF, pF, pS);
        scan_reduce_kernel<<<64, 256, 0, stream>>>(
            pF, pS, coefF, fast0, slow0, outP + LOGITS_N + (size_t)l * SLn * D_,
            outP + LOGITS_N + (size_t)Lc * SLn * D_ + (size_t)l * SLn * D_);
        gemm(stream, 128, 64, qrB, wOutT + (size_t)l * H_ * 1536, b_out + l * H_, outF, H_,
             nullptr, 0, S_, H_, 1536, 5);
        ln_kernel<<<S_, 256, 0, stream>>>(hF, outF, ln1_g + l * H_, ln1_b + l * H_, hF, hB);
        gemm(stream, 128, 128, hB, f1T + (size_t)l * I_ * H_, ffn_b1 + l * I_, nullptr, 0, ffn1B,
             I_, S_, I_, H_, 11);
        gemm(stream, 128, 64, ffn1B, f2T + (size_t)l * H_ * I_, ffn_b2 + l * H_, outF, H_,
             nullptr, 0, S_, H_, I_, 5);
        ln_kernel<<<S_, 256, 0, stream>>>(hF, outF, ln2_g + l * H_, ln2_b + l * H_, hF, hB);
    }
    ln_kernel<<<S_, 256, 0, stream>>>(hF, nullptr, fln_g, fln_b, nullptr, hB);
    gemm(stream, 128, 128, hB, embB, nullptr, outP, V_, nullptr, 0, S_, V_, H_, 4);
}

// Round 3
// 1047.370 us; speedup vs baseline: 1.6998x; 1.2339x over previous
//
#include <hip/hip_runtime.h>
#include <hip/hip_bf16.h>
#include <stdint.h>

typedef __hip_bfloat16 bf16;
typedef float f32x4 __attribute__((ext_vector_type(4)));
typedef short s16x8 __attribute__((ext_vector_type(8)));
typedef short s16x4 __attribute__((ext_vector_type(4)));

#define DEV __device__ __forceinline__

static constexpr int S_ = 2048, H_ = 1024, D_ = 512, I_ = 4096, V_ = 32000;
static constexpr int SLn = 32, Lc = 2;
static constexpr size_t LOGITS_N = (size_t)S_ * V_;

DEV float gelu_f(float x) {
    float x3 = x * x * x;
    return 0.5f * x * (1.f + tanhf(0.7978845608028654f * (x + 0.044715f * x3)));
}

#define AS1(p) ((const __attribute__((address_space(1))) void*)(uintptr_t)(p))
#define AS3(p) ((__attribute__((address_space(3))) void*)(uint32_t)(uintptr_t)(p))

// ===================== logits GEMM: 8-phase 256x256 BK=64 ====================
// C[2048,32000] = A[2048,1024](lda) @ BT[32000,1024]^T, f32 out.
// T1 XCD swizzle, T2 st_16x32 LDS swizzle (inverse-swizzled global src +
// swizzled ds_read), T3/T4 phase-split with counted vmcnt(2), T5 setprio.
__global__ __launch_bounds__(512, 2) void logits_gemm8(const bf16* __restrict__ A, int lda,
                                                       const bf16* __restrict__ BT,
                                                       float* __restrict__ C) {
    __shared__ short Asm[2][256 * 64];
    __shared__ short Bsm[2][256 * 64];
    const int tid = threadIdx.x;
    const int lane = tid & 63;
    const int wid = tid >> 6;
    const int wm = wid >> 2, wn = wid & 3;  // 2 x 4 waves; wave C = 128 x 64

    int bid = blockIdx.x;                 // grid = 1000
    int wgid = (bid & 7) * 125 + (bid >> 3);  // bijective XCD chunking
    const int m0 = (wgid & 7) * 256;
    const int n0 = (wgid >> 3) * 256;

    // staging: thread writes LDS linear 16B at c*8192 + tid*16; global source
    // is inverse-st_16x32-swizzled so swizzled ds_reads see the right data.
    int rowS[4], colS[4];
#pragma unroll
    for (int c = 0; c < 4; ++c) {
        int L = c * 8192 + tid * 16;
        int sidx = L >> 10;
        int w = L & 1023;
        int r16 = w >> 6;
        int c2 = (w & 63) ^ (((r16 >> 3) & 1) << 5);
        rowS[c] = (sidx >> 1) * 16 + r16;
        colS[c] = ((sidx & 1) * 64 + c2) >> 1;
    }
    const bf16 *aSrc[4], *bSrc[4];
#pragma unroll
    for (int c = 0; c < 4; ++c) {
        aSrc[c] = A + (size_t)(m0 + rowS[c]) * lda + colS[c];
        bSrc[c] = BT + (size_t)(n0 + rowS[c]) * 1024 + colS[c];
    }

    // swizzled per-lane ds_read offset (shorts)
    const int laneoff = ((lane & 15) * 64 + (((lane >> 4) * 8) ^ (((lane >> 3) & 1) << 4)) * 2) >> 1;

    f32x4 acc[8][4];
#pragma unroll
    for (int i = 0; i < 8; i++)
#pragma unroll
        for (int j = 0; j < 4; j++)
#pragma unroll
            for (int r = 0; r < 4; r++) acc[i][j][r] = 0.f;

#define STAGE_A(c, b, kt) \
    __builtin_amdgcn_global_load_lds(AS1(aSrc[c] + (kt) * 64), AS3(&Asm[b][(c) * 4096 + tid * 8]), 16, 0, 0)
#define STAGE_B(c, b, kt) \
    __builtin_amdgcn_global_load_lds(AS1(bSrc[c] + (kt) * 64), AS3(&Bsm[b][(c) * 4096 + tid * 8]), 16, 0, 0)

    // prologue: tile 0 -> buf 0
#pragma unroll
    for (int c = 0; c < 4; ++c) {
        STAGE_A(c, 0, 0);
        STAGE_B(c, 0, 0);
    }

    const int NT = 16;  // K=1024 / BK=64
    for (int t = 0; t < NT; ++t) {
        const int b = t & 1;
        const short* As = Asm[b];
        const short* Bs = Bsm[b];
        s16x8 af[4][2], bfr[2][2];

        // ---- phase 0: quadrant (mq=0, nq=0); stage piece {A0,B0} of t+1 ----
        if (t + 1 < NT) {
            STAGE_A(0, b ^ 1, t + 1);
            STAGE_B(0, b ^ 1, t + 1);
            asm volatile("s_waitcnt vmcnt(2)" ::: "memory");
        } else {
            asm volatile("s_waitcnt vmcnt(0)" ::: "memory");
        }
        __builtin_amdgcn_s_barrier();
#pragma unroll
        for (int fi = 0; fi < 4; ++fi)
#pragma unroll
            for (int ks = 0; ks < 2; ++ks)
                af[fi][ks] = *(const s16x8*)&As[((wm * 8 + fi) * 2 + ks) * 512 + laneoff];
#pragma unroll
        for (int fj = 0; fj < 2; ++fj)
#pragma unroll
            for (int ks = 0; ks < 2; ++ks)
                bfr[fj][ks] = *(const s16x8*)&Bs[((wn * 4 + fj) * 2 + ks) * 512 + laneoff];
        __builtin_amdgcn_s_barrier();
        __builtin_amdgcn_s_setprio(1);
#pragma unroll
        for (int fi = 0; fi < 4; ++fi)
#pragma unroll
            for (int fj = 0; fj < 2; ++fj)
#pragma unroll
                for (int ks = 0; ks < 2; ++ks)
                    acc[fi][fj] = __builtin_amdgcn_mfma_f32_16x16x32_bf16(af[fi][ks], bfr[fj][ks], acc[fi][fj], 0, 0, 0);
        __builtin_amdgcn_s_setprio(0);
        __builtin_amdgcn_s_barrier();

        // ---- phase 1: quadrant (0,1); stage {A1,B1} ----
        if (t + 1 < NT) {
            STAGE_A(1, b ^ 1, t + 1);
            STAGE_B(1, b ^ 1, t + 1);
        }
#pragma unroll
        for (int fj = 0; fj < 2; ++fj)
#pragma unroll
            for (int ks = 0; ks < 2; ++ks)
                bfr[fj][ks] = *(const s16x8*)&Bs[((wn * 4 + 2 + fj) * 2 + ks) * 512 + laneoff];
        __builtin_amdgcn_s_barrier();
        __builtin_amdgcn_s_setprio(1);
#pragma unroll
        for (int fi = 0; fi < 4; ++fi)
#pragma unroll
            for (int fj = 0; fj < 2; ++fj)
#pragma unroll
                for (int ks = 0; ks < 2; ++ks)
                    acc[fi][2 + fj] = __builtin_amdgcn_mfma_f32_16x16x32_bf16(af[fi][ks], bfr[fj][ks], acc[fi][2 + fj], 0, 0, 0);
        __builtin_amdgcn_s_setprio(0);
        __builtin_amdgcn_s_barrier();

        // ---- phase 2: quadrant (1,0); stage {A2,B2} ----
        if (t + 1 < NT) {
            STAGE_A(2, b ^ 1, t + 1);
            STAGE_B(2, b ^ 1, t + 1);
        }
#pragma unroll
        for (int fi = 0; fi < 4; ++fi)
#pragma unroll
            for (int ks = 0; ks < 2; ++ks)
                af[fi][ks] = *(const s16x8*)&As[((wm * 8 + 4 + fi) * 2 + ks) * 512 + laneoff];
#pragma unroll
        for (int fj = 0; fj < 2; ++fj)
#pragma unroll
            for (int ks = 0; ks < 2; ++ks)
                bfr[fj][ks] = *(const s16x8*)&Bs[((wn * 4 + fj) * 2 + ks) * 512 + laneoff];
        __builtin_amdgcn_s_barrier();
        __builtin_amdgcn_s_setprio(1);
#pragma unroll
        for (int fi = 0; fi < 4; ++fi)
#pragma unroll
            for (int fj = 0; fj < 2; ++fj)
#pragma unroll
                for (int ks = 0; ks < 2; ++ks)
                    acc[4 + fi][fj] = __builtin_amdgcn_mfma_f32_16x16x32_bf16(af[fi][ks], bfr[fj][ks], acc[4 + fi][fj], 0, 0, 0);
        __builtin_amdgcn_s_setprio(0);
        __builtin_amdgcn_s_barrier();

        // ---- phase 3: quadrant (1,1); stage {A3,B3} ----
        if (t + 1 < NT) {
            STAGE_A(3, b ^ 1, t + 1);
            STAGE_B(3, b ^ 1, t + 1);
        }
#pragma unroll
        for (int fj = 0; fj < 2; ++fj)
#pragma unroll
            for (int ks = 0; ks < 2; ++ks)
                bfr[fj][ks] = *(const s16x8*)&Bs[((wn * 4 + 2 + fj) * 2 + ks) * 512 + laneoff];
        __builtin_amdgcn_s_barrier();
        __builtin_amdgcn_s_setprio(1);
#pragma unroll
        for (int fi = 0; fi < 4; ++fi)
#pragma unroll
            for (int fj = 0; fj < 2; ++fj)
#pragma unroll
                for (int ks = 0; ks < 2; ++ks)
                    acc[4 + fi][2 + fj] = __builtin_amdgcn_mfma_f32_16x16x32_bf16(af[fi][ks], bfr[fj][ks], acc[4 + fi][2 + fj], 0, 0, 0);
        __builtin_amdgcn_s_setprio(0);
        __builtin_amdgcn_s_barrier();
    }
#undef STAGE_A
#undef STAGE_B

#pragma unroll
    for (int fi = 0; fi < 8; ++fi) {
        int gr = m0 + wm * 128 + fi * 16 + ((lane >> 4) << 2);
#pragma unroll
        for (int fj = 0; fj < 4; ++fj) {
            int gc = n0 + wn * 64 + fj * 16 + (lane & 15);
#pragma unroll
            for (int r = 0; r < 4; ++r) C[(size_t)(gr + r) * V_ + gc] = acc[fi][fj][r];
        }
    }
}

// ------------------------------ GEMM (NT) ----------------------------------
// C[M,N] = A[M,K](lda) @ BT[N,K]^T (+bias,+gelu). 2-phase double-buffered.
// FLAGS: 1=bias, 2=gelu, 4=store f32, 8=store bf16
template <int BM, int BN, int FLAGS>
__global__ __launch_bounds__(256) void gemm_nt(const bf16* __restrict__ A, int lda,
                                               const bf16* __restrict__ BT,
                                               const float* __restrict__ bias,
                                               float* __restrict__ Cf, int ldf,
                                               bf16* __restrict__ Cb, int ldb2,
                                               int K, int Mt, int Nt) {
    constexpr int FM = BM / 32, FN = BN / 32;
    constexpr int CA = BM / 64, CB = BN / 64;
    __shared__ short As[2 * BM * 32];
    __shared__ short Bs[2 * BN * 32];
    const int tid = threadIdx.x;
    const int lane = tid & 63;
    const int wm = (tid >> 6) >> 1, wn = (tid >> 6) & 1;

    int nwg = Mt * Nt;
    int bid = blockIdx.x, wgid = bid;
    if ((nwg & 7) == 0) {
        int cpx = nwg >> 3;
        wgid = (bid & 7) * cpx + (bid >> 3);
    }
    const int m0 = (wgid % Mt) * BM, n0 = (wgid / Mt) * BN;

    f32x4 acc[FM][FN];
#pragma unroll
    for (int i = 0; i < FM; i++)
#pragma unroll
        for (int j = 0; j < FN; j++)
#pragma unroll
            for (int r = 0; r < 4; r++) acc[i][j][r] = 0.f;

    auto stage = [&](int kt, int buf) {
        short* as = As + buf * (BM * 32);
        short* bs = Bs + buf * (BN * 32);
#pragma unroll
        for (int h = 0; h < CA; ++h) {
            int j = tid + h * 256;
            int row = j >> 2, kc = j & 3;
            const bf16* ga = A + (size_t)(m0 + row) * lda + kt * 32 + kc * 8;
            __builtin_amdgcn_global_load_lds(AS1(ga), AS3(&as[j * 8]), 16, 0, 0);
        }
#pragma unroll
        for (int h = 0; h < CB; ++h) {
            int j = tid + h * 256;
            int row = j >> 2, kc = j & 3;
            const bf16* gb = BT + (size_t)(n0 + row) * K + kt * 32 + kc * 8;
            __builtin_amdgcn_global_load_lds(AS1(gb), AS3(&bs[j * 8]), 16, 0, 0);
        }
    };
    auto compute = [&](int buf) {
        const short* as = As + buf * (BM * 32);
        const short* bs = Bs + buf * (BN * 32);
        s16x8 a[FM], b[FN];
#pragma unroll
        for (int i = 0; i < FM; i++)
            a[i] = *(const s16x8*)&as[(wm * (BM / 2) + i * 16 + (lane & 15)) * 32 + (lane >> 4) * 8];
#pragma unroll
        for (int j = 0; j < FN; j++)
            b[j] = *(const s16x8*)&bs[(wn * (BN / 2) + j * 16 + (lane & 15)) * 32 + (lane >> 4) * 8];
#pragma unroll
        for (int i = 0; i < FM; i++)
#pragma unroll
            for (int j = 0; j < FN; j++)
                acc[i][j] = __builtin_amdgcn_mfma_f32_16x16x32_bf16(a[i], b[j], acc[i][j], 0, 0, 0);
    };

    const int nk = K >> 5;
    stage(0, 0);
    asm volatile("s_waitcnt vmcnt(0)" ::: "memory");
    __syncthreads();
    int cur = 0;
    for (int kt = 0; kt < nk - 1; ++kt) {
        stage(kt + 1, cur ^ 1);
        compute(cur);
        asm volatile("s_waitcnt vmcnt(0)" ::: "memory");
        __syncthreads();
        cur ^= 1;
    }
    compute(cur);

#pragma unroll
    for (int i = 0; i < FM; i++) {
        int gr0 = m0 + wm * (BM / 2) + i * 16 + ((lane >> 4) << 2);
#pragma unroll
        for (int j = 0; j < FN; j++) {
            int gc = n0 + wn * (BN / 2) + j * 16 + (lane & 15);
            float bv = (FLAGS & 1) ? bias[gc] : 0.f;
#pragma unroll
            for (int r = 0; r < 4; r++) {
                float v = acc[i][j][r] + bv;
                if (FLAGS & 2) v = gelu_f(v);
                if (FLAGS & 4) Cf[(size_t)(gr0 + r) * ldf + gc] = v;
                if (FLAGS & 8) Cb[(size_t)(gr0 + r) * ldb2 + gc] = __float2bfloat16(v);
            }
        }
    }
}

// ------------------------ transpose f32 -> bf16^T ---------------------------
__global__ __launch_bounds__(256) void transpose_bf16_kernel(const float* __restrict__ W,
                                                             bf16* __restrict__ WT, int K, int N) {
    __shared__ float t[32][33];
    int tx = threadIdx.x & 31, ty = threadIdx.x >> 5;
    int kb = blockIdx.y * 32, nb = blockIdx.x * 32;
#pragma unroll
    for (int i = 0; i < 4; i++)
        t[ty + 8 * i][tx] = W[(size_t)(kb + ty + 8 * i) * N + nb + tx];
    __syncthreads();
#pragma unroll
    for (int i = 0; i < 4; i++)
        WT[(size_t)(nb + ty + 8 * i) * K + kb + tx] = __float2bfloat16(t[tx][ty + 8 * i]);
}

// ------------------------------ f32 -> bf16 ---------------------------------
__global__ void conv_bf16_kernel(const float* __restrict__ src, bf16* __restrict__ dst) {
    size_t i = (size_t)blockIdx.x * 256 + threadIdx.x;
    f32x4 v = ((const f32x4*)src)[i];
    s16x4 o;
#pragma unroll
    for (int j = 0; j < 4; j++) {
        bf16 h = __float2bfloat16(v[j]);
        o[j] = *(short*)&h;
    }
    ((s16x4*)dst)[i] = o;
}

// ------------------------------ embedding ----------------------------------
__global__ void embed_kernel(const int* __restrict__ ids, const float* __restrict__ emb,
                             const float* __restrict__ pos, float* __restrict__ hF,
                             bf16* __restrict__ hB) {
    int t = blockIdx.x, tid = threadIdx.x;
    int id = ids[t];
    f32x4 v = ((const f32x4*)(emb + (size_t)id * H_))[tid];
    f32x4 q = ((const f32x4*)(pos + (size_t)t * H_))[tid];
    v = v + q;
    ((f32x4*)(hF + (size_t)t * H_))[tid] = v;
    s16x4 o;
#pragma unroll
    for (int j = 0; j < 4; j++) {
        bf16 h = __float2bfloat16(v[j]);
        o[j] = *(short*)&h;
    }
    ((s16x4*)(hB + (size_t)t * 1536))[tid] = o;  // strided into hrB
}

// ------------------------------ LayerNorm ----------------------------------
__global__ __launch_bounds__(256) void ln_kernel(const float* __restrict__ x,
                                                 const float* __restrict__ res,
                                                 const float* __restrict__ g,
                                                 const float* __restrict__ b,
                                                 float* __restrict__ of, bf16* __restrict__ ob,
                                                 int ldo) {
    __shared__ float red[8];
    int row = blockIdx.x, tid = threadIdx.x, lane = tid & 63, wid = tid >> 6;
    const float* xr = x + (size_t)row * H_;
    float v[4];
#pragma unroll
    for (int j = 0; j < 4; j++) {
        int c = tid + 256 * j;
        v[j] = xr[c] + (res ? res[(size_t)row * H_ + c] : 0.f);
    }
    float s = v[0] + v[1] + v[2] + v[3];
#pragma unroll
    for (int o = 32; o; o >>= 1) s += __shfl_xor(s, o);
    if (!lane) red[wid] = s;
    __syncthreads();
    float mean = (red[0] + red[1] + red[2] + red[3]) * (1.f / H_);
    float q = 0.f;
#pragma unroll
    for (int j = 0; j < 4; j++) {
        float d = v[j] - mean;
        q += d * d;
    }
#pragma unroll
    for (int o = 32; o; o >>= 1) q += __shfl_xor(q, o);
    if (!lane) red[4 + wid] = q;
    __syncthreads();
    float var = (red[4] + red[5] + red[6] + red[7]) * (1.f / H_);
    float rstd = rsqrtf(var + 1e-5f);
#pragma unroll
    for (int j = 0; j < 4; j++) {
        int c = tid + 256 * j;
        float o2 = (v[j] - mean) * rstd * g[c] + b[c];
        if (of) of[(size_t)row * H_ + c] = o2;
        if (ob) ob[(size_t)row * ldo + c] = __float2bfloat16(o2);
    }
}

// --------------------- mem transpose for attn scores ------------------------
__global__ void memt_kernel(const float* __restrict__ fast0, const float* __restrict__ slow0,
                            float* __restrict__ memT) {
    int idx = blockIdx.x * 256 + threadIdx.x;
    int d = idx >> 6, n = idx & 63;
    const float* m = (n < 32) ? fast0 + (size_t)n * D_ : slow0 + (size_t)(n - 32) * D_;
    memT[idx] = m[d];
}

// ---------------- attention (fused keynorm), 1 q-row per wave ---------------
__global__ __launch_bounds__(256) void attn_kernel(const float* __restrict__ keys,
                                                   const float* __restrict__ memT,
                                                   const float* __restrict__ fast0,
                                                   const float* __restrict__ slow0,
                                                   bf16* __restrict__ qr, bf16* __restrict__ hr) {
    __shared__ float klds[4][512];
    int wid = threadIdx.x >> 6, lane = threadIdx.x & 63;
    int r = blockIdx.x * 4 + wid;
    float kv[8], ss = 0.f;
#pragma unroll
    for (int j = 0; j < 8; j++) {
        kv[j] = keys[(size_t)r * D_ + lane + 64 * j];
        ss += kv[j] * kv[j];
    }
#pragma unroll
    for (int o = 32; o; o >>= 1) ss += __shfl_xor(ss, o);
    float inv = 1.f / (sqrtf(ss) + 1e-6f);
#pragma unroll
    for (int j = 0; j < 8; j++) {
        kv[j] *= inv;
        klds[wid][lane + 64 * j] = kv[j];
    }
    __syncthreads();
    float s0 = 0.f, s1 = 0.f, s2 = 0.f, s3 = 0.f;
#pragma unroll 8
    for (int d = 0; d < 512; d += 4) {
        s0 = fmaf(klds[wid][d + 0], memT[(d + 0) * 64 + lane], s0);
        s1 = fmaf(klds[wid][d + 1], memT[(d + 1) * 64 + lane], s1);
        s2 = fmaf(klds[wid][d + 2], memT[(d + 2) * 64 + lane], s2);
        s3 = fmaf(klds[wid][d + 3], memT[(d + 3) * 64 + lane], s3);
    }
    float s = (s0 + s1 + s2 + s3) * 0.044194173824159216f;
    float m = s;
#pragma unroll
    for (int o = 32; o; o >>= 1) m = fmaxf(m, __shfl_xor(m, o));
    float p = expf(s - m);
    float sum = p;
#pragma unroll
    for (int o = 32; o; o >>= 1) sum += __shfl_xor(sum, o);
    float pn = p / sum;
    float rv[8];
#pragma unroll
    for (int j = 0; j < 8; j++) rv[j] = 0.f;
    for (int n2 = 0; n2 < 64; ++n2) {
        float a2 = __shfl(pn, n2);
        const float* m2 = (n2 < 32) ? (fast0 + (size_t)n2 * D_) : (slow0 + (size_t)(n2 - 32) * D_);
#pragma unroll
        for (int j = 0; j < 8; j++) rv[j] = fmaf(a2, m2[lane + 64 * j], rv[j]);
    }
#pragma unroll
    for (int j = 0; j < 8; j++) {
        bf16 o = __float2bfloat16(rv[j] * kv[j]);
        qr[(size_t)r * 1536 + 1024 + lane + 64 * j] = o;
        hr[(size_t)r * 1536 + 1024 + lane + 64 * j] = o;
    }
}

// ------------------------- scan coefficients --------------------------------
__global__ void coef_kernel(float* __restrict__ coef) {
    int t = blockIdx.x * 256 + threadIdx.x;
    int j0 = (t + 9) / 10;
    float a = powf(0.9f, (float)(2047 - t + 205 - j0));
    float b = 0.f;
    for (int j = j0; j < 205; ++j)
        b += powf(0.9f, (float)(10 * j - t + j - j0)) * powf(0.99f, (float)(204 - j));
    b *= 0.1f;
    coef[t] = a;
    coef[2048 + t] = b;
    if (t == 0) {
        coef[4096] = powf(0.99f, 205.f);
        float cfs = 0.f;
        for (int j = 0; j < 205; ++j)
            cfs += powf(0.9f, (float)(11 * j + 1)) * powf(0.99f, (float)(204 - j));
        coef[4097] = 0.1f * cfs;
    }
}

// -------------------- gates epilogue: sigmoid * coef ------------------------
__global__ void sigcoef_kernel(const float* __restrict__ raw, const float* __restrict__ coef,
                               float* __restrict__ ga, float* __restrict__ gb) {
    int i = blockIdx.x * 256 + threadIdx.x;  // 2048*32
    int r = i >> 5, n = i & 31;
    float g = 1.f / (1.f + expf(-raw[r * 64 + n]));
    ga[i] = g * coef[r];
    gb[i] = g * coef[2048 + r];
}

// ------------------------- scan: split-T partial GEMMs ----------------------
// grid 256 = dg(8) x mg(2) x tc(16); partial[tc][32][512]
__global__ __launch_bounds__(256) void scan_part_kernel(const float* __restrict__ items,
                                                        const float* __restrict__ ga,
                                                        const float* __restrict__ gb,
                                                        float* __restrict__ pF,
                                                        float* __restrict__ pS) {
    int tid = threadIdx.x;
    int d = (blockIdx.x & 7) * 64 + (tid & 63);
    int mg = (blockIdx.x >> 3) & 1;
    int tc = blockIdx.x >> 4;
    int m0 = mg * 16 + (tid >> 6) * 4;
    float aF[4] = {0.f, 0.f, 0.f, 0.f}, aS[4] = {0.f, 0.f, 0.f, 0.f};
    for (int t = tc * 128; t < tc * 128 + 128; ++t) {
        float it = items[(size_t)t * D_ + d];
#pragma unroll
        for (int j = 0; j < 4; j++) {
            aF[j] = fmaf(ga[t * 32 + m0 + j], it, aF[j]);
            aS[j] = fmaf(gb[t * 32 + m0 + j], it, aS[j]);
        }
    }
#pragma unroll
    for (int j = 0; j < 4; j++) {
        pF[((size_t)tc * 32 + m0 + j) * D_ + d] = aF[j];
        pS[((size_t)tc * 32 + m0 + j) * D_ + d] = aS[j];
    }
}

__global__ __launch_bounds__(256) void scan_reduce_kernel(const float* __restrict__ pF,
                                                          const float* __restrict__ pS,
                                                          const float* __restrict__ coef,
                                                          const float* __restrict__ fast0,
                                                          const float* __restrict__ slow0,
                                                          float* __restrict__ fastO,
                                                          float* __restrict__ slowO) {
    int i = blockIdx.x * 256 + threadIdx.x;  // 16384
    float f = 0.f, s = 0.f;
#pragma unroll
    for (int c = 0; c < 16; c++) {
        f += pF[(size_t)c * 32 * D_ + i];
        s += pS[(size_t)c * 32 * D_ + i];
    }
    fastO[i] = f;
    slowO[i] = s + coef[4096] * slow0[i] + coef[4097] * fast0[i];
}

// ------------------------------- host side ----------------------------------
static inline void gemm(hipStream_t st, int BM, int BN, const bf16* A, int lda, const bf16* BT,
                        const float* bias, float* Cf, int ldf, bf16* Cb, int ldb2,
                        int M, int N, int K, int flags) {
    int Mt = M / BM, Nt = N / BN;
    dim3 g(Mt * Nt), b(256);
#define GCASE(bm, bn, fl)                                                                       \
    if (BM == bm && BN == bn && flags == fl) {                                                  \
        gemm_nt<bm, bn, fl><<<g, b, 0, st>>>(A, lda, BT, bias, Cf, ldf, Cb, ldb2, K, Mt, Nt);   \
        return;                                                                                 \
    }
    GCASE(128, 128, 11)
    GCASE(128, 64, 9)
    GCASE(128, 64, 11)
    GCASE(128, 64, 5)
    GCASE(64, 64, 13)
    GCASE(64, 64, 5)
#undef GCASE
}

static inline void transp(hipStream_t st, const float* W, bf16* WT, int K, int N) {
    transpose_bf16_kernel<<<dim3(N / 32, K / 32), 256, 0, st>>>(W, WT, K, N);
}

extern "C" void kernel_launch(void* const* d_in, const int* in_sizes, int n_in,
                              void* d_out, int out_size, void* d_ws, size_t ws_size,
                              hipStream_t stream) {
    const int* ids = (const int*)d_in[0];
    const float* fastS = (const float*)d_in[1];
    const float* slowS = (const float*)d_in[2];
    const float* emb = (const float*)d_in[3];
    const float* pos = (const float*)d_in[4];
    const float* W_item = (const float*)d_in[5];
    const float* b_item = (const float*)d_in[6];
    const float* W_q = (const float*)d_in[7];
    const float* b_q = (const float*)d_in[8];
    const float* rh_W1 = (const float*)d_in[9];
    const float* rh_b1 = (const float*)d_in[10];
    const float* rh_W2 = (const float*)d_in[11];
    const float* rh_b2 = (const float*)d_in[12];
    const float* gate_W = (const float*)d_in[13];
    const float* gate_b = (const float*)d_in[14];
    const float* W_out = (const float*)d_in[15];
    const float* b_out = (const float*)d_in[16];
    const float* ln1_g = (const float*)d_in[17];
    const float* ln1_b = (const float*)d_in[18];
    const float* ffn_W1 = (const float*)d_in[19];
    const float* ffn_b1 = (const float*)d_in[20];
    const float* ffn_W2 = (const float*)d_in[21];
    const float* ffn_b2 = (const float*)d_in[22];
    const float* ln2_g = (const float*)d_in[23];
    const float* ln2_b = (const float*)d_in[24];
    const float* fln_g = (const float*)d_in[25];
    const float* fln_b = (const float*)d_in[26];
    float* outP = (float*)d_out;

    size_t off = 0;
    char* base = (char*)d_ws;
    auto alloc = [&](size_t n) -> char* {
        char* p = base + off;
        off += (n + 255) & ~(size_t)255;
        return p;
    };
    bf16* wItemT = (bf16*)alloc((size_t)Lc * D_ * H_ * 2);
    bf16* wQT = (bf16*)alloc((size_t)Lc * H_ * H_ * 2);
    bf16* rh1T = (bf16*)alloc((size_t)Lc * (2 * D_) * D_ * 2);
    bf16* rh2T = (bf16*)alloc((size_t)Lc * D_ * (2 * D_) * 2);
    bf16* wOutT = (bf16*)alloc((size_t)Lc * H_ * 1536 * 2);
    bf16* f1T = (bf16*)alloc((size_t)Lc * I_ * H_ * 2);
    bf16* f2T = (bf16*)alloc((size_t)Lc * H_ * I_ * 2);
    bf16* gWT = (bf16*)alloc((size_t)Lc * 64 * 1536 * 2);
    bf16* embB = (bf16*)alloc((size_t)V_ * H_ * 2);
    float* hF = (float*)alloc((size_t)S_ * H_ * 4);
    bf16* hrB = (bf16*)alloc((size_t)S_ * 1536 * 2);  // [h | retrieved]
    bf16* hB = hrB;                                   // h part, ld=1536
    float* itemsF = (float*)alloc((size_t)S_ * D_ * 4);
    bf16* itemsB = (bf16*)alloc((size_t)S_ * D_ * 2);
    bf16* qrB = (bf16*)alloc((size_t)S_ * 1536 * 2);  // [query | retrieved]
    bf16* k1B = (bf16*)alloc((size_t)S_ * (2 * D_) * 2);
    float* keysF = (float*)alloc((size_t)S_ * D_ * 4);
    float* outF = (float*)alloc((size_t)S_ * H_ * 4);
    bf16* ffn1B = (bf16*)alloc((size_t)S_ * I_ * 2);
    float* gRawF = (float*)alloc((size_t)S_ * 64 * 4);
    float* gaF = (float*)alloc((size_t)S_ * SLn * 4);
    float* gbF = (float*)alloc((size_t)S_ * SLn * 4);
    float* coefF = (float*)alloc(4200 * 4);
    float* memT = (float*)alloc((size_t)D_ * 64 * 4);
    float* pF = (float*)alloc((size_t)16 * SLn * D_ * 4);
    float* pS = (float*)alloc((size_t)16 * SLn * D_ * 4);

    coef_kernel<<<8, 256, 0, stream>>>(coefF);
    for (int l = 0; l < Lc; ++l) {
        transp(stream, W_item + (size_t)l * H_ * D_, wItemT + (size_t)l * D_ * H_, H_, D_);
        transp(stream, W_q + (size_t)l * H_ * H_, wQT + (size_t)l * H_ * H_, H_, H_);
        transp(stream, rh_W1 + (size_t)l * D_ * 2 * D_, rh1T + (size_t)l * 2 * D_ * D_, D_, 2 * D_);
        transp(stream, rh_W2 + (size_t)l * 2 * D_ * D_, rh2T + (size_t)l * D_ * 2 * D_, 2 * D_, D_);
        transp(stream, W_out + (size_t)l * 1536 * H_, wOutT + (size_t)l * H_ * 1536, 1536, H_);
        transp(stream, ffn_W1 + (size_t)l * H_ * I_, f1T + (size_t)l * I_ * H_, H_, I_);
        transp(stream, ffn_W2 + (size_t)l * I_ * H_, f2T + (size_t)l * H_ * I_, I_, H_);
        transp(stream, gate_W + (size_t)l * 1536 * 64, gWT + (size_t)l * 64 * 1536, 1536, 64);
    }
    conv_bf16_kernel<<<(int)((size_t)V_ * H_ / 4 / 256), 256, 0, stream>>>(emb, embB);
    embed_kernel<<<S_, 256, 0, stream>>>(ids, emb, pos, hF, hB);

    for (int l = 0; l < Lc; ++l) {
        const float* fast0 = fastS + (size_t)l * SLn * D_;
        const float* slow0 = slowS + (size_t)l * SLn * D_;
        gemm(stream, 64, 64, hB, 1536, wItemT + (size_t)l * D_ * H_, b_item + l * D_, itemsF, D_,
             itemsB, D_, S_, D_, H_, 13);
        gemm(stream, 128, 64, hB, 1536, wQT + (size_t)l * H_ * H_, b_q + l * H_, nullptr, 0, qrB,
             1536, S_, H_, H_, 9);
        gemm(stream, 128, 64, itemsB, D_, rh1T + (size_t)l * 2 * D_ * D_, rh_b1 + l * 2 * D_,
             nullptr, 0, k1B, 2 * D_, S_, 2 * D_, D_, 11);
        gemm(stream, 64, 64, k1B, 2 * D_, rh2T + (size_t)l * D_ * 2 * D_, rh_b2 + l * D_, keysF,
             D_, nullptr, 0, S_, D_, 2 * D_, 5);
        memt_kernel<<<128, 256, 0, stream>>>(fast0, slow0, memT);
        attn_kernel<<<S_ / 4, 256, 0, stream>>>(keysF, memT, fast0, slow0, qrB, hrB);
        gemm(stream, 64, 64, hrB, 1536, gWT + (size_t)l * 64 * 1536, gate_b + l * 64, gRawF, 64,
             nullptr, 0, S_, 64, 1536, 5);
        sigcoef_kernel<<<S_ * SLn / 256, 256, 0, stream>>>(gRawF, coefF, gaF, gbF);
        scan_part_kernel<<<256, 256, 0, stream>>>(itemsF, gaF, gbF, pF, pS);
        scan_reduce_kernel<<<64, 256, 0, stream>>>(
            pF, pS, coefF, fast0, slow0, outP + LOGITS_N + (size_t)l * SLn * D_,
            outP + LOGITS_N + (size_t)Lc * SLn * D_ + (size_t)l * SLn * D_);
        gemm(stream, 128, 64, qrB, 1536, wOutT + (size_t)l * H_ * 1536, b_out + l * H_, outF, H_,
             nullptr, 0, S_, H_, 1536, 5);
        ln_kernel<<<S_, 256, 0, stream>>>(hF, outF, ln1_g + l * H_, ln1_b + l * H_, hF, hB, 1536);
        gemm(stream, 128, 128, hB, 1536, f1T + (size_t)l * I_ * H_, ffn_b1 + l * I_, nullptr, 0,
             ffn1B, I_, S_, I_, H_, 11);
        gemm(stream, 128, 64, ffn1B, I_, f2T + (size_t)l * H_ * I_, ffn_b2 + l * H_, outF, H_,
             nullptr, 0, S_, H_, I_, 5);
        ln_kernel<<<S_, 256, 0, stream>>>(hF, outF, ln2_g + l * H_, ln2_b + l * H_, hF, hB, 1536);
    }
    ln_kernel<<<S_, 256, 0, stream>>>(hF, nullptr, fln_g, fln_b, nullptr, hB, 1536);
    logits_gemm8<<<1000, 512, 0, stream>>>(hB, 1536, embB, outP);
}

// Round 4
// 937.531 us; speedup vs baseline: 1.8990x; 1.1172x over previous
//
#include <hip/hip_runtime.h>
#include <hip/hip_bf16.h>
#include <stdint.h>

typedef __hip_bfloat16 bf16;
typedef float f32x4 __attribute__((ext_vector_type(4)));
typedef short s16x8 __attribute__((ext_vector_type(8)));
typedef short s16x4 __attribute__((ext_vector_type(4)));

#define DEV __device__ __forceinline__

static constexpr int S_ = 2048, H_ = 1024, D_ = 512, I_ = 4096, V_ = 32000;
static constexpr int SLn = 32, Lc = 2;
static constexpr size_t LOGITS_N = (size_t)S_ * V_;

DEV float gelu_f(float x) {
    float x3 = x * x * x;
    return 0.5f * x * (1.f + tanhf(0.7978845608028654f * (x + 0.044715f * x3)));
}

#define AS1(p) ((const __attribute__((address_space(1))) void*)(uintptr_t)(p))
#define AS3(p) ((__attribute__((address_space(3))) void*)(uint32_t)(uintptr_t)(p))

// ======================= unified pipelined GEMM (NT) ========================
// C[M,N] = A[M,K](lda) @ BT[N,K](ldb=K)^T. BK=32, 4 LDS buffers, 3-ahead
// prefetch with counted vmcnt (never 0 mid-loop), XOR-subtile LDS swizzle
// (0-conflict, verified R3), XCD-chunked m-fastest block swizzle, setprio.
// FLAGS: 1=bias, 2=gelu, 4=store f32, 8=store bf16
template <int BM, int BN, int TH, int WM, int WN, int FLAGS>
__global__ __launch_bounds__(TH, (TH == 512) ? 2 : 3) void gemm_p4(
    const bf16* __restrict__ A, int lda, const bf16* __restrict__ BT,
    const float* __restrict__ bias, float* __restrict__ Cf, int ldf,
    bf16* __restrict__ Cb, int ldb2, int K, int Mt, int Nt) {
    constexpr int FM = BM / (WM * 16), FN = BN / (WN * 16);
    constexpr int CA = (BM * 4) / TH, CB = (BN * 4) / TH, CH = CA + CB;
    constexpr int BUFS = (BM + BN) * 32;  // shorts per buffer
    __shared__ short lds[4 * BUFS];
    const int tid = threadIdx.x, lane = tid & 63;
    const int wm = (tid >> 6) / WN, wn = (tid >> 6) % WN;

    int nwg = Mt * Nt;
    int bid = blockIdx.x, wgid = bid;
    if ((nwg & 7) == 0) {  // bijective XCD chunking
        int cpx = nwg >> 3;
        wgid = (bid & 7) * cpx + (bid >> 3);
    }
    const int m0 = (wgid % Mt) * BM, n0 = (wgid / Mt) * BN;

    // per-lane global sources, inverse-swizzled so linear gload_lds dest +
    // swizzled ds_read line up (both-sides rule).
    const bf16* aS[CA];
    const bf16* bS[CB];
#pragma unroll
    for (int c = 0; c < CA; ++c) {
        int L = (c * TH + tid) * 16;
        int sidx = L >> 10, w = L & 1023;
        int r16 = w >> 6;
        int c2 = (w & 63) ^ (((r16 >> 3) & 1) << 5);
        aS[c] = A + (size_t)(m0 + sidx * 16 + r16) * lda + (c2 >> 1);
    }
#pragma unroll
    for (int c = 0; c < CB; ++c) {
        int L = (c * TH + tid) * 16;
        int sidx = L >> 10, w = L & 1023;
        int r16 = w >> 6;
        int c2 = (w & 63) ^ (((r16 >> 3) & 1) << 5);
        bS[c] = BT + (size_t)(n0 + sidx * 16 + r16) * K + (c2 >> 1);
    }

    auto stage = [&](int kt) {
        short* dst = &lds[(kt & 3) * BUFS];
#pragma unroll
        for (int c = 0; c < CA; ++c)
            __builtin_amdgcn_global_load_lds(AS1(aS[c] + kt * 32), AS3(dst + (c * TH + tid) * 8), 16, 0, 0);
        short* dstB = dst + BM * 32;
#pragma unroll
        for (int c = 0; c < CB; ++c)
            __builtin_amdgcn_global_load_lds(AS1(bS[c] + kt * 32), AS3(dstB + (c * TH + tid) * 8), 16, 0, 0);
    };

    // swizzled per-lane ds_read offset (shorts) — verified 0-conflict (R3)
    const int laneoff = ((lane & 15) * 64 + ((((lane >> 4) * 8) ^ (((lane >> 3) & 1) << 4)) << 1)) >> 1;

    f32x4 acc[FM][FN];
#pragma unroll
    for (int i = 0; i < FM; i++)
#pragma unroll
        for (int j = 0; j < FN; j++)
#pragma unroll
            for (int r = 0; r < 4; r++) acc[i][j][r] = 0.f;

    const int NT = K >> 5;
    stage(0);
    stage(1);
    stage(2);
    for (int t = 0; t < NT; ++t) {
        if (t + 3 < NT) stage(t + 3);
        const int rem = NT - 1 - t;
        if (rem >= 3)
            asm volatile("s_waitcnt vmcnt(%0)" ::"n"(3 * CH) : "memory");
        else if (rem == 2)
            asm volatile("s_waitcnt vmcnt(%0)" ::"n"(2 * CH) : "memory");
        else if (rem == 1)
            asm volatile("s_waitcnt vmcnt(%0)" ::"n"(CH) : "memory");
        else
            asm volatile("s_waitcnt vmcnt(0)" ::: "memory");
        __builtin_amdgcn_s_barrier();

        const short* as = &lds[(t & 3) * BUFS];
        const short* bs = as + BM * 32;
        s16x8 af[FM], bf[FN];
#pragma unroll
        for (int i = 0; i < FM; i++) af[i] = *(const s16x8*)&as[(wm * FM + i) * 512 + laneoff];
#pragma unroll
        for (int j = 0; j < FN; j++) bf[j] = *(const s16x8*)&bs[(wn * FN + j) * 512 + laneoff];
        __builtin_amdgcn_s_setprio(1);
#pragma unroll
        for (int i = 0; i < FM; i++)
#pragma unroll
            for (int j = 0; j < FN; j++)
                acc[i][j] = __builtin_amdgcn_mfma_f32_16x16x32_bf16(af[i], bf[j], acc[i][j], 0, 0, 0);
        __builtin_amdgcn_s_setprio(0);
        __builtin_amdgcn_s_barrier();
    }

#pragma unroll
    for (int i = 0; i < FM; i++) {
        int gr0 = m0 + (wm * FM + i) * 16 + ((lane >> 4) << 2);
#pragma unroll
        for (int j = 0; j < FN; j++) {
            int gc = n0 + (wn * FN + j) * 16 + (lane & 15);
            float bv = (FLAGS & 1) ? bias[gc] : 0.f;
#pragma unroll
            for (int r = 0; r < 4; r++) {
                float v = acc[i][j][r] + bv;
                if (FLAGS & 2) v = gelu_f(v);
                if (FLAGS & 4) Cf[(size_t)(gr0 + r) * ldf + gc] = v;
                if (FLAGS & 8) Cb[(size_t)(gr0 + r) * ldb2 + gc] = __float2bfloat16(v);
            }
        }
    }
}

// ------------------------ transpose f32 -> bf16^T ---------------------------
__global__ __launch_bounds__(256) void transpose_bf16_kernel(const float* __restrict__ W,
                                                             bf16* __restrict__ WT, int K, int N) {
    __shared__ float t[32][33];
    int tx = threadIdx.x & 31, ty = threadIdx.x >> 5;
    int kb = blockIdx.y * 32, nb = blockIdx.x * 32;
#pragma unroll
    for (int i = 0; i < 4; i++)
        t[ty + 8 * i][tx] = W[(size_t)(kb + ty + 8 * i) * N + nb + tx];
    __syncthreads();
#pragma unroll
    for (int i = 0; i < 4; i++)
        WT[(size_t)(nb + ty + 8 * i) * K + kb + tx] = __float2bfloat16(t[tx][ty + 8 * i]);
}

// ------------------------------ f32 -> bf16 ---------------------------------
__global__ void conv_bf16_kernel(const float* __restrict__ src, bf16* __restrict__ dst) {
    size_t i = (size_t)blockIdx.x * 256 + threadIdx.x;
    f32x4 v = ((const f32x4*)src)[i];
    s16x4 o;
#pragma unroll
    for (int j = 0; j < 4; j++) {
        bf16 h = __float2bfloat16(v[j]);
        o[j] = *(short*)&h;
    }
    ((s16x4*)dst)[i] = o;
}

// ------------------------------ embedding ----------------------------------
__global__ void embed_kernel(const int* __restrict__ ids, const float* __restrict__ emb,
                             const float* __restrict__ pos, float* __restrict__ hF,
                             bf16* __restrict__ hB) {
    int t = blockIdx.x, tid = threadIdx.x;
    int id = ids[t];
    f32x4 v = ((const f32x4*)(emb + (size_t)id * H_))[tid];
    f32x4 q = ((const f32x4*)(pos + (size_t)t * H_))[tid];
    v = v + q;
    ((f32x4*)(hF + (size_t)t * H_))[tid] = v;
    s16x4 o;
#pragma unroll
    for (int j = 0; j < 4; j++) {
        bf16 h = __float2bfloat16(v[j]);
        o[j] = *(short*)&h;
    }
    ((s16x4*)(hB + (size_t)t * 1536))[tid] = o;  // strided into hrB
}

// ------------------------------ LayerNorm ----------------------------------
__global__ __launch_bounds__(256) void ln_kernel(const float* __restrict__ x,
                                                 const float* __restrict__ res,
                                                 const float* __restrict__ g,
                                                 const float* __restrict__ b,
                                                 float* __restrict__ of, bf16* __restrict__ ob,
                                                 int ldo) {
    __shared__ float red[8];
    int row = blockIdx.x, tid = threadIdx.x, lane = tid & 63, wid = tid >> 6;
    const float* xr = x + (size_t)row * H_;
    float v[4];
#pragma unroll
    for (int j = 0; j < 4; j++) {
        int c = tid + 256 * j;
        v[j] = xr[c] + (res ? res[(size_t)row * H_ + c] : 0.f);
    }
    float s = v[0] + v[1] + v[2] + v[3];
#pragma unroll
    for (int o = 32; o; o >>= 1) s += __shfl_xor(s, o);
    if (!lane) red[wid] = s;
    __syncthreads();
    float mean = (red[0] + red[1] + red[2] + red[3]) * (1.f / H_);
    float q = 0.f;
#pragma unroll
    for (int j = 0; j < 4; j++) {
        float d = v[j] - mean;
        q += d * d;
    }
#pragma unroll
    for (int o = 32; o; o >>= 1) q += __shfl_xor(q, o);
    if (!lane) red[4 + wid] = q;
    __syncthreads();
    float var = (red[4] + red[5] + red[6] + red[7]) * (1.f / H_);
    float rstd = rsqrtf(var + 1e-5f);
#pragma unroll
    for (int j = 0; j < 4; j++) {
        int c = tid + 256 * j;
        float o2 = (v[j] - mean) * rstd * g[c] + b[c];
        if (of) of[(size_t)row * H_ + c] = o2;
        if (ob) ob[(size_t)row * ldo + c] = __float2bfloat16(o2);
    }
}

// --------------------- mem transpose for attn scores ------------------------
__global__ void memt_kernel(const float* __restrict__ fast0, const float* __restrict__ slow0,
                            float* __restrict__ memT) {
    int idx = blockIdx.x * 256 + threadIdx.x;
    int d = idx >> 6, n = idx & 63;
    const float* m = (n < 32) ? fast0 + (size_t)n * D_ : slow0 + (size_t)(n - 32) * D_;
    memT[idx] = m[d];
}

// ---------------- attention (fused keynorm), 1 q-row per wave ---------------
__global__ __launch_bounds__(256) void attn_kernel(const float* __restrict__ keys,
                                                   const float* __restrict__ memT,
                                                   const float* __restrict__ fast0,
                                                   const float* __restrict__ slow0,
                                                   bf16* __restrict__ qr, bf16* __restrict__ hr) {
    __shared__ float klds[4][512];
    int wid = threadIdx.x >> 6, lane = threadIdx.x & 63;
    int r = blockIdx.x * 4 + wid;
    float kv[8], ss = 0.f;
#pragma unroll
    for (int j = 0; j < 8; j++) {
        kv[j] = keys[(size_t)r * D_ + lane + 64 * j];
        ss += kv[j] * kv[j];
    }
#pragma unroll
    for (int o = 32; o; o >>= 1) ss += __shfl_xor(ss, o);
    float inv = 1.f / (sqrtf(ss) + 1e-6f);
#pragma unroll
    for (int j = 0; j < 8; j++) {
        kv[j] *= inv;
        klds[wid][lane + 64 * j] = kv[j];
    }
    __syncthreads();
    float s0 = 0.f, s1 = 0.f, s2 = 0.f, s3 = 0.f;
#pragma unroll 8
    for (int d = 0; d < 512; d += 4) {
        s0 = fmaf(klds[wid][d + 0], memT[(d + 0) * 64 + lane], s0);
        s1 = fmaf(klds[wid][d + 1], memT[(d + 1) * 64 + lane], s1);
        s2 = fmaf(klds[wid][d + 2], memT[(d + 2) * 64 + lane], s2);
        s3 = fmaf(klds[wid][d + 3], memT[(d + 3) * 64 + lane], s3);
    }
    float s = (s0 + s1 + s2 + s3) * 0.044194173824159216f;
    float m = s;
#pragma unroll
    for (int o = 32; o; o >>= 1) m = fmaxf(m, __shfl_xor(m, o));
    float p = expf(s - m);
    float sum = p;
#pragma unroll
    for (int o = 32; o; o >>= 1) sum += __shfl_xor(sum, o);
    float pn = p / sum;
    float rv[8];
#pragma unroll
    for (int j = 0; j < 8; j++) rv[j] = 0.f;
    for (int n2 = 0; n2 < 64; ++n2) {
        float a2 = __shfl(pn, n2);
        const float* m2 = (n2 < 32) ? (fast0 + (size_t)n2 * D_) : (slow0 + (size_t)(n2 - 32) * D_);
#pragma unroll
        for (int j = 0; j < 8; j++) rv[j] = fmaf(a2, m2[lane + 64 * j], rv[j]);
    }
#pragma unroll
    for (int j = 0; j < 8; j++) {
        bf16 o = __float2bfloat16(rv[j] * kv[j]);
        qr[(size_t)r * 1536 + 1024 + lane + 64 * j] = o;
        hr[(size_t)r * 1536 + 1024 + lane + 64 * j] = o;
    }
}

// ------------------------- scan coefficients --------------------------------
__global__ void coef_kernel(float* __restrict__ coef) {
    int t = blockIdx.x * 256 + threadIdx.x;
    int j0 = (t + 9) / 10;
    float a = powf(0.9f, (float)(2047 - t + 205 - j0));
    float b = 0.f;
    for (int j = j0; j < 205; ++j)
        b += powf(0.9f, (float)(10 * j - t + j - j0)) * powf(0.99f, (float)(204 - j));
    b *= 0.1f;
    coef[t] = a;
    coef[2048 + t] = b;
    if (t == 0) {
        coef[4096] = powf(0.99f, 205.f);
        float cfs = 0.f;
        for (int j = 0; j < 205; ++j)
            cfs += powf(0.9f, (float)(11 * j + 1)) * powf(0.99f, (float)(204 - j));
        coef[4097] = 0.1f * cfs;
    }
}

// -------------------- gates epilogue: sigmoid * coef ------------------------
__global__ void sigcoef_kernel(const float* __restrict__ raw, const float* __restrict__ coef,
                               float* __restrict__ ga, float* __restrict__ gb) {
    int i = blockIdx.x * 256 + threadIdx.x;  // 2048*32
    int r = i >> 5, n = i & 31;
    float g = 1.f / (1.f + expf(-raw[r * 64 + n]));
    ga[i] = g * coef[r];
    gb[i] = g * coef[2048 + r];
}

// ------------------------- scan: split-T partial GEMMs ----------------------
__global__ __launch_bounds__(256) void scan_part_kernel(const float* __restrict__ items,
                                                        const float* __restrict__ ga,
                                                        const float* __restrict__ gb,
                                                        float* __restrict__ pF,
                                                        float* __restrict__ pS) {
    int tid = threadIdx.x;
    int d = (blockIdx.x & 7) * 64 + (tid & 63);
    int mg = (blockIdx.x >> 3) & 1;
    int tc = blockIdx.x >> 4;
    int m0 = mg * 16 + (tid >> 6) * 4;
    float aF[4] = {0.f, 0.f, 0.f, 0.f}, aS[4] = {0.f, 0.f, 0.f, 0.f};
    for (int t = tc * 128; t < tc * 128 + 128; ++t) {
        float it = items[(size_t)t * D_ + d];
#pragma unroll
        for (int j = 0; j < 4; j++) {
            aF[j] = fmaf(ga[t * 32 + m0 + j], it, aF[j]);
            aS[j] = fmaf(gb[t * 32 + m0 + j], it, aS[j]);
        }
    }
#pragma unroll
    for (int j = 0; j < 4; j++) {
        pF[((size_t)tc * 32 + m0 + j) * D_ + d] = aF[j];
        pS[((size_t)tc * 32 + m0 + j) * D_ + d] = aS[j];
    }
}

__global__ __launch_bounds__(256) void scan_reduce_kernel(const float* __restrict__ pF,
                                                          const float* __restrict__ pS,
                                                          const float* __restrict__ coef,
                                                          const float* __restrict__ fast0,
                                                          const float* __restrict__ slow0,
                                                          float* __restrict__ fastO,
                                                          float* __restrict__ slowO) {
    int i = blockIdx.x * 256 + threadIdx.x;  // 16384
    float f = 0.f, s = 0.f;
#pragma unroll
    for (int c = 0; c < 16; c++) {
        f += pF[(size_t)c * 32 * D_ + i];
        s += pS[(size_t)c * 32 * D_ + i];
    }
    fastO[i] = f;
    slowO[i] = s + coef[4096] * slow0[i] + coef[4097] * fast0[i];
}

// ------------------------------- host side ----------------------------------
static inline void gemmM(hipStream_t st, const bf16* A, int lda, const bf16* BT,
                         const float* bias, float* Cf, int ldf, bf16* Cb, int ldb2,
                         int M, int N, int K, int flags) {
    int Mt = M / 128, Nt = N / 64;
    dim3 g(Mt * Nt), b(256);
#define GCASE(fl)                                                                             \
    if (flags == fl) {                                                                        \
        gemm_p4<128, 64, 256, 2, 2, fl><<<g, b, 0, st>>>(A, lda, BT, bias, Cf, ldf, Cb, ldb2, \
                                                         K, Mt, Nt);                          \
        return;                                                                               \
    }
    GCASE(13)
    GCASE(9)
    GCASE(11)
    GCASE(5)
#undef GCASE
}

static inline void transp(hipStream_t st, const float* W, bf16* WT, int K, int N) {
    transpose_bf16_kernel<<<dim3(N / 32, K / 32), 256, 0, st>>>(W, WT, K, N);
}

extern "C" void kernel_launch(void* const* d_in, const int* in_sizes, int n_in,
                              void* d_out, int out_size, void* d_ws, size_t ws_size,
                              hipStream_t stream) {
    const int* ids = (const int*)d_in[0];
    const float* fastS = (const float*)d_in[1];
    const float* slowS = (const float*)d_in[2];
    const float* emb = (const float*)d_in[3];
    const float* pos = (const float*)d_in[4];
    const float* W_item = (const float*)d_in[5];
    const float* b_item = (const float*)d_in[6];
    const float* W_q = (const float*)d_in[7];
    const float* b_q = (const float*)d_in[8];
    const float* rh_W1 = (const float*)d_in[9];
    const float* rh_b1 = (const float*)d_in[10];
    const float* rh_W2 = (const float*)d_in[11];
    const float* rh_b2 = (const float*)d_in[12];
    const float* gate_W = (const float*)d_in[13];
    const float* gate_b = (const float*)d_in[14];
    const float* W_out = (const float*)d_in[15];
    const float* b_out = (const float*)d_in[16];
    const float* ln1_g = (const float*)d_in[17];
    const float* ln1_b = (const float*)d_in[18];
    const float* ffn_W1 = (const float*)d_in[19];
    const float* ffn_b1 = (const float*)d_in[20];
    const float* ffn_W2 = (const float*)d_in[21];
    const float* ffn_b2 = (const float*)d_in[22];
    const float* ln2_g = (const float*)d_in[23];
    const float* ln2_b = (const float*)d_in[24];
    const float* fln_g = (const float*)d_in[25];
    const float* fln_b = (const float*)d_in[26];
    float* outP = (float*)d_out;

    size_t off = 0;
    char* base = (char*)d_ws;
    auto alloc = [&](size_t n) -> char* {
        char* p = base + off;
        off += (n + 255) & ~(size_t)255;
        return p;
    };
    bf16* wItemT = (bf16*)alloc((size_t)Lc * D_ * H_ * 2);
    bf16* wQT = (bf16*)alloc((size_t)Lc * H_ * H_ * 2);
    bf16* rh1T = (bf16*)alloc((size_t)Lc * (2 * D_) * D_ * 2);
    bf16* rh2T = (bf16*)alloc((size_t)Lc * D_ * (2 * D_) * 2);
    bf16* wOutT = (bf16*)alloc((size_t)Lc * H_ * 1536 * 2);
    bf16* f1T = (bf16*)alloc((size_t)Lc * I_ * H_ * 2);
    bf16* f2T = (bf16*)alloc((size_t)Lc * H_ * I_ * 2);
    bf16* gWT = (bf16*)alloc((size_t)Lc * 64 * 1536 * 2);
    bf16* embB = (bf16*)alloc((size_t)V_ * H_ * 2);
    float* hF = (float*)alloc((size_t)S_ * H_ * 4);
    bf16* hrB = (bf16*)alloc((size_t)S_ * 1536 * 2);  // [h | retrieved]
    bf16* hB = hrB;                                   // h part, ld=1536
    float* itemsF = (float*)alloc((size_t)S_ * D_ * 4);
    bf16* itemsB = (bf16*)alloc((size_t)S_ * D_ * 2);
    bf16* qrB = (bf16*)alloc((size_t)S_ * 1536 * 2);  // [query | retrieved]
    bf16* k1B = (bf16*)alloc((size_t)S_ * (2 * D_) * 2);
    float* keysF = (float*)alloc((size_t)S_ * D_ * 4);
    float* outF = (float*)alloc((size_t)S_ * H_ * 4);
    bf16* ffn1B = (bf16*)alloc((size_t)S_ * I_ * 2);
    float* gRawF = (float*)alloc((size_t)S_ * 64 * 4);
    float* gaF = (float*)alloc((size_t)S_ * SLn * 4);
    float* gbF = (float*)alloc((size_t)S_ * SLn * 4);
    float* coefF = (float*)alloc(4200 * 4);
    float* memT = (float*)alloc((size_t)D_ * 64 * 4);
    float* pF = (float*)alloc((size_t)16 * SLn * D_ * 4);
    float* pS = (float*)alloc((size_t)16 * SLn * D_ * 4);

    coef_kernel<<<8, 256, 0, stream>>>(coefF);
    for (int l = 0; l < Lc; ++l) {
        transp(stream, W_item + (size_t)l * H_ * D_, wItemT + (size_t)l * D_ * H_, H_, D_);
        transp(stream, W_q + (size_t)l * H_ * H_, wQT + (size_t)l * H_ * H_, H_, H_);
        transp(stream, rh_W1 + (size_t)l * D_ * 2 * D_, rh1T + (size_t)l * 2 * D_ * D_, D_, 2 * D_);
        transp(stream, rh_W2 + (size_t)l * 2 * D_ * D_, rh2T + (size_t)l * D_ * 2 * D_, 2 * D_, D_);
        transp(stream, W_out + (size_t)l * 1536 * H_, wOutT + (size_t)l * H_ * 1536, 1536, H_);
        transp(stream, ffn_W1 + (size_t)l * H_ * I_, f1T + (size_t)l * I_ * H_, H_, I_);
        transp(stream, ffn_W2 + (size_t)l * I_ * H_, f2T + (size_t)l * H_ * I_, I_, H_);
        transp(stream, gate_W + (size_t)l * 1536 * 64, gWT + (size_t)l * 64 * 1536, 1536, 64);
    }
    conv_bf16_kernel<<<(int)((size_t)V_ * H_ / 4 / 256), 256, 0, stream>>>(emb, embB);
    embed_kernel<<<S_, 256, 0, stream>>>(ids, emb, pos, hF, hB);

    for (int l = 0; l < Lc; ++l) {
        const float* fast0 = fastS + (size_t)l * SLn * D_;
        const float* slow0 = slowS + (size_t)l * SLn * D_;
        gemmM(stream, hB, 1536, wItemT + (size_t)l * D_ * H_, b_item + l * D_, itemsF, D_,
              itemsB, D_, S_, D_, H_, 13);
        gemmM(stream, hB, 1536, wQT + (size_t)l * H_ * H_, b_q + l * H_, nullptr, 0, qrB, 1536,
              S_, H_, H_, 9);
        gemmM(stream, itemsB, D_, rh1T + (size_t)l * 2 * D_ * D_, rh_b1 + l * 2 * D_, nullptr, 0,
              k1B, 2 * D_, S_, 2 * D_, D_, 11);
        gemmM(stream, k1B, 2 * D_, rh2T + (size_t)l * D_ * 2 * D_, rh_b2 + l * D_, keysF, D_,
              nullptr, 0, S_, D_, 2 * D_, 5);
        memt_kernel<<<128, 256, 0, stream>>>(fast0, slow0, memT);
        attn_kernel<<<S_ / 4, 256, 0, stream>>>(keysF, memT, fast0, slow0, qrB, hrB);
        gemmM(stream, hrB, 1536, gWT + (size_t)l * 64 * 1536, gate_b + l * 64, gRawF, 64,
              nullptr, 0, S_, 64, 1536, 5);
        sigcoef_kernel<<<S_ * SLn / 256, 256, 0, stream>>>(gRawF, coefF, gaF, gbF);
        scan_part_kernel<<<256, 256, 0, stream>>>(itemsF, gaF, gbF, pF, pS);
        scan_reduce_kernel<<<64, 256, 0, stream>>>(
            pF, pS, coefF, fast0, slow0, outP + LOGITS_N + (size_t)l * SLn * D_,
            outP + LOGITS_N + (size_t)Lc * SLn * D_ + (size_t)l * SLn * D_);
        gemmM(stream, qrB, 1536, wOutT + (size_t)l * H_ * 1536, b_out + l * H_, outF, H_,
              nullptr, 0, S_, H_, 1536, 5);
        ln_kernel<<<S_, 256, 0, stream>>>(hF, outF, ln1_g + l * H_, ln1_b + l * H_, hF, hB, 1536);
        gemmM(stream, hB, 1536, f1T + (size_t)l * I_ * H_, ffn_b1 + l * I_, nullptr, 0, ffn1B,
              I_, S_, I_, H_, 11);
        gemmM(stream, ffn1B, I_, f2T + (size_t)l * H_ * I_, ffn_b2 + l * H_, outF, H_, nullptr,
              0, S_, H_, I_, 5);
        ln_kernel<<<S_, 256, 0, stream>>>(hF, outF, ln2_g + l * H_, ln2_b + l * H_, hF, hB, 1536);
    }
    ln_kernel<<<S_, 256, 0, stream>>>(hF, nullptr, fln_g, fln_b, nullptr, hB, 1536);
    // logits: 256x256 8-wave instance, grid 8x125 = 1000
    gemm_p4<256, 256, 512, 2, 4, 4><<<1000, 512, 0, stream>>>(hB, 1536, embB, nullptr, outP, V_,
                                                              nullptr, 0, H_, 8, 125);
}

// Round 5
// 923.824 us; speedup vs baseline: 1.9272x; 1.0148x over previous
//
#include <hip/hip_runtime.h>
#include <hip/hip_bf16.h>
#include <stdint.h>

typedef __hip_bfloat16 bf16;
typedef float f32x4 __attribute__((ext_vector_type(4)));
typedef short s16x8 __attribute__((ext_vector_type(8)));
typedef short s16x4 __attribute__((ext_vector_type(4)));

#define DEV __device__ __forceinline__

static constexpr int S_ = 2048, H_ = 1024, D_ = 512, I_ = 4096, V_ = 32000;
static constexpr int SLn = 32, Lc = 2;
static constexpr size_t LOGITS_N = (size_t)S_ * V_;

DEV float gelu_f(float x) {
    float x3 = x * x * x;
    return 0.5f * x * (1.f + tanhf(0.7978845608028654f * (x + 0.044715f * x3)));
}

#define AS1(p) ((const __attribute__((address_space(1))) void*)(uintptr_t)(p))
#define AS3(p) ((__attribute__((address_space(3))) void*)(uint32_t)(uintptr_t)(p))

// ======================= unified pipelined GEMM (NT) ========================
// C[M,N] = A[M,K](lda) @ BT[N,K](ldb=K)^T. BK=32, 4 LDS slots, 3-ahead
// prefetch, counted vmcnt once per K-tile (never 0 mid-loop), m201 phase body:
// {ds_read ; stage ; [vmcnt] ; s_barrier ; sched_barrier ; MFMA ; s_barrier}.
// XOR-subtile LDS swizzle (0-conflict, verified R3/R4), XCD-chunked m-fastest
// block swizzle, setprio around MFMA cluster.
// FLAGS: 1=bias, 2=gelu, 4=store f32, 8=store bf16
template <int BM, int BN, int TH, int WM, int WN, int FLAGS>
__global__ __launch_bounds__(TH, (TH == 512) ? 2 : 3) void gemm_p5(
    const bf16* __restrict__ A, int lda, const bf16* __restrict__ BT,
    const float* __restrict__ bias, float* __restrict__ Cf, int ldf,
    bf16* __restrict__ Cb, int ldb2, int K, int Mt, int Nt) {
    constexpr int FM = BM / (WM * 16), FN = BN / (WN * 16);
    constexpr int CA = (BM * 4) / TH, CB = (BN * 4) / TH, CH = CA + CB;
    constexpr int NPH = (FM * FN >= 32) ? 2 : 1;  // phases per K-tile
    constexpr int FMP = FM / NPH;
    constexpr int BUFS = (BM + BN) * 32;  // shorts per slot
    __shared__ short lds[4 * BUFS];
    const int tid = threadIdx.x, lane = tid & 63;
    const int wm = (tid >> 6) / WN, wn = (tid >> 6) % WN;

    int nwg = Mt * Nt;
    int bid = blockIdx.x, wgid = bid;
    if ((nwg & 7) == 0) {  // bijective XCD chunking
        int cpx = nwg >> 3;
        wgid = (bid & 7) * cpx + (bid >> 3);
    }
    const int m0 = (wgid % Mt) * BM, n0 = (wgid / Mt) * BN;

    // per-lane global sources, inverse-swizzled so linear gload_lds dest +
    // swizzled ds_read line up (both-sides rule).
    const bf16* aS[CA];
    const bf16* bS[CB];
#pragma unroll
    for (int c = 0; c < CA; ++c) {
        int L = (c * TH + tid) * 16;
        int sidx = L >> 10, w = L & 1023;
        int r16 = w >> 6;
        int c2 = (w & 63) ^ (((r16 >> 3) & 1) << 5);
        aS[c] = A + (size_t)(m0 + sidx * 16 + r16) * lda + (c2 >> 1);
    }
#pragma unroll
    for (int c = 0; c < CB; ++c) {
        int L = (c * TH + tid) * 16;
        int sidx = L >> 10, w = L & 1023;
        int r16 = w >> 6;
        int c2 = (w & 63) ^ (((r16 >> 3) & 1) << 5);
        bS[c] = BT + (size_t)(n0 + sidx * 16 + r16) * K + (c2 >> 1);
    }

    auto stageA = [&](int kt) {
        short* dst = &lds[(kt & 3) * BUFS];
#pragma unroll
        for (int c = 0; c < CA; ++c)
            __builtin_amdgcn_global_load_lds(AS1(aS[c] + kt * 32), AS3(dst + (c * TH + tid) * 8), 16, 0, 0);
    };
    auto stageB = [&](int kt) {
        short* dst = &lds[(kt & 3) * BUFS + BM * 32];
#pragma unroll
        for (int c = 0; c < CB; ++c)
            __builtin_amdgcn_global_load_lds(AS1(bS[c] + kt * 32), AS3(dst + (c * TH + tid) * 8), 16, 0, 0);
    };

    // swizzled per-lane ds_read offset (shorts) — verified 0-conflict (R3/R4)
    const int laneoff = ((lane & 15) * 64 + ((((lane >> 4) * 8) ^ (((lane >> 3) & 1) << 4)) << 1)) >> 1;

    f32x4 acc[FM][FN];
#pragma unroll
    for (int i = 0; i < FM; i++)
#pragma unroll
        for (int j = 0; j < FN; j++)
#pragma unroll
            for (int r = 0; r < 4; r++) acc[i][j][r] = 0.f;

    const int NT = K >> 5;
    stageA(0); stageB(0);
    stageA(1); stageB(1);
    stageA(2); stageB(2);
    asm volatile("s_waitcnt vmcnt(%0)" ::"n"(2 * CH) : "memory");
    __builtin_amdgcn_s_barrier();

    for (int t = 0; t < NT; ++t) {
        const short* as = &lds[(t & 3) * BUFS];
        const short* bs = as + BM * 32;
        s16x8 bf[FN];
#pragma unroll
        for (int p = 0; p < NPH; ++p) {
            // --- ds_read this phase's operands (pre-barrier: latency hides
            // under barrier-wait + other waves' MFMA clusters) ---
            s16x8 af[FMP];
#pragma unroll
            for (int i = 0; i < FMP; i++)
                af[i] = *(const s16x8*)&as[(wm * FM + p * FMP + i) * 512 + laneoff];
            if (p == 0) {
#pragma unroll
                for (int j = 0; j < FN; j++)
                    bf[j] = *(const s16x8*)&bs[(wn * FN + j) * 512 + laneoff];
            }
            // --- stage chunk of tile t+3 into the slot freed at tile t-1 ---
            if (t + 3 < NT) {
                if (NPH == 1) {
                    stageA(t + 3);
                    stageB(t + 3);
                } else if (p == 0) {
                    stageA(t + 3);
                } else {
                    stageB(t + 3);
                }
            }
            // --- tile-boundary counted vmcnt: tile t+1 must have landed;
            // tiles t+2, t+3 stay in flight ---
            if (p == NPH - 1 && t + 1 < NT) {
                const int ahead = NT - 2 - t;
                if (ahead >= 2)
                    asm volatile("s_waitcnt vmcnt(%0)" ::"n"(2 * CH) : "memory");
                else if (ahead == 1)
                    asm volatile("s_waitcnt vmcnt(%0)" ::"n"(CH) : "memory");
                else
                    asm volatile("s_waitcnt vmcnt(0)" ::: "memory");
            }
            __builtin_amdgcn_s_barrier();
            __builtin_amdgcn_sched_barrier(0);  // pin MFMA cluster below barrier
            __builtin_amdgcn_s_setprio(1);
#pragma unroll
            for (int i = 0; i < FMP; i++)
#pragma unroll
                for (int j = 0; j < FN; j++)
                    acc[p * FMP + i][j] =
                        __builtin_amdgcn_mfma_f32_16x16x32_bf16(af[i], bf[j], acc[p * FMP + i][j], 0, 0, 0);
            __builtin_amdgcn_s_setprio(0);
            __builtin_amdgcn_s_barrier();
        }
    }

#pragma unroll
    for (int i = 0; i < FM; i++) {
        int gr0 = m0 + (wm * FM + i) * 16 + ((lane >> 4) << 2);
#pragma unroll
        for (int j = 0; j < FN; j++) {
            int gc = n0 + (wn * FN + j) * 16 + (lane & 15);
            float bv = (FLAGS & 1) ? bias[gc] : 0.f;
#pragma unroll
            for (int r = 0; r < 4; r++) {
                float v = acc[i][j][r] + bv;
                if (FLAGS & 2) v = gelu_f(v);
                if (FLAGS & 4) Cf[(size_t)(gr0 + r) * ldf + gc] = v;
                if (FLAGS & 8) Cb[(size_t)(gr0 + r) * ldb2 + gc] = __float2bfloat16(v);
            }
        }
    }
}

// ------------------------ transpose f32 -> bf16^T ---------------------------
__global__ __launch_bounds__(256) void transpose_bf16_kernel(const float* __restrict__ W,
                                                             bf16* __restrict__ WT, int K, int N) {
    __shared__ float t[32][33];
    int tx = threadIdx.x & 31, ty = threadIdx.x >> 5;
    int kb = blockIdx.y * 32, nb = blockIdx.x * 32;
#pragma unroll
    for (int i = 0; i < 4; i++)
        t[ty + 8 * i][tx] = W[(size_t)(kb + ty + 8 * i) * N + nb + tx];
    __syncthreads();
#pragma unroll
    for (int i = 0; i < 4; i++)
        WT[(size_t)(nb + ty + 8 * i) * K + kb + tx] = __float2bfloat16(t[tx][ty + 8 * i]);
}

// ------------------------------ f32 -> bf16 ---------------------------------
__global__ void conv_bf16_kernel(const float* __restrict__ src, bf16* __restrict__ dst) {
    size_t i = (size_t)blockIdx.x * 256 + threadIdx.x;
    f32x4 v = ((const f32x4*)src)[i];
    s16x4 o;
#pragma unroll
    for (int j = 0; j < 4; j++) {
        bf16 h = __float2bfloat16(v[j]);
        o[j] = *(short*)&h;
    }
    ((s16x4*)dst)[i] = o;
}

// ------------------------------ embedding ----------------------------------
__global__ void embed_kernel(const int* __restrict__ ids, const float* __restrict__ emb,
                             const float* __restrict__ pos, float* __restrict__ hF,
                             bf16* __restrict__ hB) {
    int t = blockIdx.x, tid = threadIdx.x;
    int id = ids[t];
    f32x4 v = ((const f32x4*)(emb + (size_t)id * H_))[tid];
    f32x4 q = ((const f32x4*)(pos + (size_t)t * H_))[tid];
    v = v + q;
    ((f32x4*)(hF + (size_t)t * H_))[tid] = v;
    s16x4 o;
#pragma unroll
    for (int j = 0; j < 4; j++) {
        bf16 h = __float2bfloat16(v[j]);
        o[j] = *(short*)&h;
    }
    ((s16x4*)(hB + (size_t)t * 1536))[tid] = o;  // strided into hrB
}

// ------------------------------ LayerNorm ----------------------------------
__global__ __launch_bounds__(256) void ln_kernel(const float* __restrict__ x,
                                                 const float* __restrict__ res,
                                                 const float* __restrict__ g,
                                                 const float* __restrict__ b,
                                                 float* __restrict__ of, bf16* __restrict__ ob,
                                                 int ldo) {
    __shared__ float red[8];
    int row = blockIdx.x, tid = threadIdx.x, lane = tid & 63, wid = tid >> 6;
    const float* xr = x + (size_t)row * H_;
    float v[4];
#pragma unroll
    for (int j = 0; j < 4; j++) {
        int c = tid + 256 * j;
        v[j] = xr[c] + (res ? res[(size_t)row * H_ + c] : 0.f);
    }
    float s = v[0] + v[1] + v[2] + v[3];
#pragma unroll
    for (int o = 32; o; o >>= 1) s += __shfl_xor(s, o);
    if (!lane) red[wid] = s;
    __syncthreads();
    float mean = (red[0] + red[1] + red[2] + red[3]) * (1.f / H_);
    float q = 0.f;
#pragma unroll
    for (int j = 0; j < 4; j++) {
        float d = v[j] - mean;
        q += d * d;
    }
#pragma unroll
    for (int o = 32; o; o >>= 1) q += __shfl_xor(q, o);
    if (!lane) red[4 + wid] = q;
    __syncthreads();
    float var = (red[4] + red[5] + red[6] + red[7]) * (1.f / H_);
    float rstd = rsqrtf(var + 1e-5f);
#pragma unroll
    for (int j = 0; j < 4; j++) {
        int c = tid + 256 * j;
        float o2 = (v[j] - mean) * rstd * g[c] + b[c];
        if (of) of[(size_t)row * H_ + c] = o2;
        if (ob) ob[(size_t)row * ldo + c] = __float2bfloat16(o2);
    }
}

// --------------------- mem transpose for attn scores ------------------------
__global__ void memt_kernel(const float* __restrict__ fast0, const float* __restrict__ slow0,
                            float* __restrict__ memT) {
    int idx = blockIdx.x * 256 + threadIdx.x;
    int d = idx >> 6, n = idx & 63;
    const float* m = (n < 32) ? fast0 + (size_t)n * D_ : slow0 + (size_t)(n - 32) * D_;
    memT[idx] = m[d];
}

// ---------------- attention (fused keynorm), 1 q-row per wave ---------------
__global__ __launch_bounds__(256) void attn_kernel(const float* __restrict__ keys,
                                                   const float* __restrict__ memT,
                                                   const float* __restrict__ fast0,
                                                   const float* __restrict__ slow0,
                                                   bf16* __restrict__ qr, bf16* __restrict__ hr) {
    __shared__ float klds[4][512];
    int wid = threadIdx.x >> 6, lane = threadIdx.x & 63;
    int r = blockIdx.x * 4 + wid;
    float kv[8], ss = 0.f;
#pragma unroll
    for (int j = 0; j < 8; j++) {
        kv[j] = keys[(size_t)r * D_ + lane + 64 * j];
        ss += kv[j] * kv[j];
    }
#pragma unroll
    for (int o = 32; o; o >>= 1) ss += __shfl_xor(ss, o);
    float inv = 1.f / (sqrtf(ss) + 1e-6f);
#pragma unroll
    for (int j = 0; j < 8; j++) {
        kv[j] *= inv;
        klds[wid][lane + 64 * j] = kv[j];
    }
    __syncthreads();
    float s0 = 0.f, s1 = 0.f, s2 = 0.f, s3 = 0.f;
#pragma unroll 8
    for (int d = 0; d < 512; d += 4) {
        s0 = fmaf(klds[wid][d + 0], memT[(d + 0) * 64 + lane], s0);
        s1 = fmaf(klds[wid][d + 1], memT[(d + 1) * 64 + lane], s1);
        s2 = fmaf(klds[wid][d + 2], memT[(d + 2) * 64 + lane], s2);
        s3 = fmaf(klds[wid][d + 3], memT[(d + 3) * 64 + lane], s3);
    }
    float s = (s0 + s1 + s2 + s3) * 0.044194173824159216f;
    float m = s;
#pragma unroll
    for (int o = 32; o; o >>= 1) m = fmaxf(m, __shfl_xor(m, o));
    float p = expf(s - m);
    float sum = p;
#pragma unroll
    for (int o = 32; o; o >>= 1) sum += __shfl_xor(sum, o);
    float pn = p / sum;
    float rv[8];
#pragma unroll
    for (int j = 0; j < 8; j++) rv[j] = 0.f;
    for (int n2 = 0; n2 < 64; ++n2) {
        float a2 = __shfl(pn, n2);
        const float* m2 = (n2 < 32) ? (fast0 + (size_t)n2 * D_) : (slow0 + (size_t)(n2 - 32) * D_);
#pragma unroll
        for (int j = 0; j < 8; j++) rv[j] = fmaf(a2, m2[lane + 64 * j], rv[j]);
    }
#pragma unroll
    for (int j = 0; j < 8; j++) {
        bf16 o = __float2bfloat16(rv[j] * kv[j]);
        qr[(size_t)r * 1536 + 1024 + lane + 64 * j] = o;
        hr[(size_t)r * 1536 + 1024 + lane + 64 * j] = o;
    }
}

// ------------------------- scan coefficients --------------------------------
__global__ void coef_kernel(float* __restrict__ coef) {
    int t = blockIdx.x * 256 + threadIdx.x;
    int j0 = (t + 9) / 10;
    float a = powf(0.9f, (float)(2047 - t + 205 - j0));
    float b = 0.f;
    for (int j = j0; j < 205; ++j)
        b += powf(0.9f, (float)(10 * j - t + j - j0)) * powf(0.99f, (float)(204 - j));
    b *= 0.1f;
    coef[t] = a;
    coef[2048 + t] = b;
    if (t == 0) {
        coef[4096] = powf(0.99f, 205.f);
        float cfs = 0.f;
        for (int j = 0; j < 205; ++j)
            cfs += powf(0.9f, (float)(11 * j + 1)) * powf(0.99f, (float)(204 - j));
        coef[4097] = 0.1f * cfs;
    }
}

// -------------------- gates epilogue: sigmoid * coef ------------------------
__global__ void sigcoef_kernel(const float* __restrict__ raw, const float* __restrict__ coef,
                               float* __restrict__ ga, float* __restrict__ gb) {
    int i = blockIdx.x * 256 + threadIdx.x;  // 2048*32
    int r = i >> 5, n = i & 31;
    float g = 1.f / (1.f + expf(-raw[r * 64 + n]));
    ga[i] = g * coef[r];
    gb[i] = g * coef[2048 + r];
}

// ------------------------- scan: split-T partial GEMMs ----------------------
__global__ __launch_bounds__(256) void scan_part_kernel(const float* __restrict__ items,
                                                        const float* __restrict__ ga,
                                                        const float* __restrict__ gb,
                                                        float* __restrict__ pF,
                                                        float* __restrict__ pS) {
    int tid = threadIdx.x;
    int d = (blockIdx.x & 7) * 64 + (tid & 63);
    int mg = (blockIdx.x >> 3) & 1;
    int tc = blockIdx.x >> 4;
    int m0 = mg * 16 + (tid >> 6) * 4;
    float aF[4] = {0.f, 0.f, 0.f, 0.f}, aS[4] = {0.f, 0.f, 0.f, 0.f};
    for (int t = tc * 128; t < tc * 128 + 128; ++t) {
        float it = items[(size_t)t * D_ + d];
#pragma unroll
        for (int j = 0; j < 4; j++) {
            aF[j] = fmaf(ga[t * 32 + m0 + j], it, aF[j]);
            aS[j] = fmaf(gb[t * 32 + m0 + j], it, aS[j]);
        }
    }
#pragma unroll
    for (int j = 0; j < 4; j++) {
        pF[((size_t)tc * 32 + m0 + j) * D_ + d] = aF[j];
        pS[((size_t)tc * 32 + m0 + j) * D_ + d] = aS[j];
    }
}

__global__ __launch_bounds__(256) void scan_reduce_kernel(const float* __restrict__ pF,
                                                          const float* __restrict__ pS,
                                                          const float* __restrict__ coef,
                                                          const float* __restrict__ fast0,
                                                          const float* __restrict__ slow0,
                                                          float* __restrict__ fastO,
                                                          float* __restrict__ slowO) {
    int i = blockIdx.x * 256 + threadIdx.x;  // 16384
    float f = 0.f, s = 0.f;
#pragma unroll
    for (int c = 0; c < 16; c++) {
        f += pF[(size_t)c * 32 * D_ + i];
        s += pS[(size_t)c * 32 * D_ + i];
    }
    fastO[i] = f;
    slowO[i] = s + coef[4096] * slow0[i] + coef[4097] * fast0[i];
}

// ------------------------------- host side ----------------------------------
static inline void gemmM(hipStream_t st, const bf16* A, int lda, const bf16* BT,
                         const float* bias, float* Cf, int ldf, bf16* Cb, int ldb2,
                         int M, int N, int K, int flags) {
    int Mt = M / 128, Nt = N / 64;
    dim3 g(Mt * Nt), b(256);
#define GCASE(fl)                                                                             \
    if (flags == fl) {                                                                        \
        gemm_p5<128, 64, 256, 2, 2, fl><<<g, b, 0, st>>>(A, lda, BT, bias, Cf, ldf, Cb, ldb2, \
                                                         K, Mt, Nt);                          \
        return;                                                                               \
    }
    GCASE(13)
    GCASE(9)
    GCASE(11)
    GCASE(5)
#undef GCASE
}

static inline void transp(hipStream_t st, const float* W, bf16* WT, int K, int N) {
    transpose_bf16_kernel<<<dim3(N / 32, K / 32), 256, 0, st>>>(W, WT, K, N);
}

extern "C" void kernel_launch(void* const* d_in, const int* in_sizes, int n_in,
                              void* d_out, int out_size, void* d_ws, size_t ws_size,
                              hipStream_t stream) {
    const int* ids = (const int*)d_in[0];
    const float* fastS = (const float*)d_in[1];
    const float* slowS = (const float*)d_in[2];
    const float* emb = (const float*)d_in[3];
    const float* pos = (const float*)d_in[4];
    const float* W_item = (const float*)d_in[5];
    const float* b_item = (const float*)d_in[6];
    const float* W_q = (const float*)d_in[7];
    const float* b_q = (const float*)d_in[8];
    const float* rh_W1 = (const float*)d_in[9];
    const float* rh_b1 = (const float*)d_in[10];
    const float* rh_W2 = (const float*)d_in[11];
    const float* rh_b2 = (const float*)d_in[12];
    const float* gate_W = (const float*)d_in[13];
    const float* gate_b = (const float*)d_in[14];
    const float* W_out = (const float*)d_in[15];
    const float* b_out = (const float*)d_in[16];
    const float* ln1_g = (const float*)d_in[17];
    const float* ln1_b = (const float*)d_in[18];
    const float* ffn_W1 = (const float*)d_in[19];
    const float* ffn_b1 = (const float*)d_in[20];
    const float* ffn_W2 = (const float*)d_in[21];
    const float* ffn_b2 = (const float*)d_in[22];
    const float* ln2_g = (const float*)d_in[23];
    const float* ln2_b = (const float*)d_in[24];
    const float* fln_g = (const float*)d_in[25];
    const float* fln_b = (const float*)d_in[26];
    float* outP = (float*)d_out;

    size_t off = 0;
    char* base = (char*)d_ws;
    auto alloc = [&](size_t n) -> char* {
        char* p = base + off;
        off += (n + 255) & ~(size_t)255;
        return p;
    };
    bf16* wItemT = (bf16*)alloc((size_t)Lc * D_ * H_ * 2);
    bf16* wQT = (bf16*)alloc((size_t)Lc * H_ * H_ * 2);
    bf16* rh1T = (bf16*)alloc((size_t)Lc * (2 * D_) * D_ * 2);
    bf16* rh2T = (bf16*)alloc((size_t)Lc * D_ * (2 * D_) * 2);
    bf16* wOutT = (bf16*)alloc((size_t)Lc * H_ * 1536 * 2);
    bf16* f1T = (bf16*)alloc((size_t)Lc * I_ * H_ * 2);
    bf16* f2T = (bf16*)alloc((size_t)Lc * H_ * I_ * 2);
    bf16* gWT = (bf16*)alloc((size_t)Lc * 64 * 1536 * 2);
    bf16* embB = (bf16*)alloc((size_t)V_ * H_ * 2);
    float* hF = (float*)alloc((size_t)S_ * H_ * 4);
    bf16* hrB = (bf16*)alloc((size_t)S_ * 1536 * 2);  // [h | retrieved]
    bf16* hB = hrB;                                   // h part, ld=1536
    float* itemsF = (float*)alloc((size_t)S_ * D_ * 4);
    bf16* itemsB = (bf16*)alloc((size_t)S_ * D_ * 2);
    bf16* qrB = (bf16*)alloc((size_t)S_ * 1536 * 2);  // [query | retrieved]
    bf16* k1B = (bf16*)alloc((size_t)S_ * (2 * D_) * 2);
    float* keysF = (float*)alloc((size_t)S_ * D_ * 4);
    float* outF = (float*)alloc((size_t)S_ * H_ * 4);
    bf16* ffn1B = (bf16*)alloc((size_t)S_ * I_ * 2);
    float* gRawF = (float*)alloc((size_t)S_ * 64 * 4);
    float* gaF = (float*)alloc((size_t)S_ * SLn * 4);
    float* gbF = (float*)alloc((size_t)S_ * SLn * 4);
    float* coefF = (float*)alloc(4200 * 4);
    float* memT = (float*)alloc((size_t)D_ * 64 * 4);
    float* pF = (float*)alloc((size_t)16 * SLn * D_ * 4);
    float* pS = (float*)alloc((size_t)16 * SLn * D_ * 4);

    coef_kernel<<<8, 256, 0, stream>>>(coefF);
    for (int l = 0; l < Lc; ++l) {
        transp(stream, W_item + (size_t)l * H_ * D_, wItemT + (size_t)l * D_ * H_, H_, D_);
        transp(stream, W_q + (size_t)l * H_ * H_, wQT + (size_t)l * H_ * H_, H_, H_);
        transp(stream, rh_W1 + (size_t)l * D_ * 2 * D_, rh1T + (size_t)l * 2 * D_ * D_, D_, 2 * D_);
        transp(stream, rh_W2 + (size_t)l * 2 * D_ * D_, rh2T + (size_t)l * D_ * 2 * D_, 2 * D_, D_);
        transp(stream, W_out + (size_t)l * 1536 * H_, wOutT + (size_t)l * H_ * 1536, 1536, H_);
        transp(stream, ffn_W1 + (size_t)l * H_ * I_, f1T + (size_t)l * I_ * H_, H_, I_);
        transp(stream, ffn_W2 + (size_t)l * I_ * H_, f2T + (size_t)l * H_ * I_, I_, H_);
        transp(stream, gate_W + (size_t)l * 1536 * 64, gWT + (size_t)l * 64 * 1536, 1536, 64);
    }
    conv_bf16_kernel<<<(int)((size_t)V_ * H_ / 4 / 256), 256, 0, stream>>>(emb, embB);
    embed_kernel<<<S_, 256, 0, stream>>>(ids, emb, pos, hF, hB);

    for (int l = 0; l < Lc; ++l) {
        const float* fast0 = fastS + (size_t)l * SLn * D_;
        const float* slow0 = slowS + (size_t)l * SLn * D_;
        gemmM(stream, hB, 1536, wItemT + (size_t)l * D_ * H_, b_item + l * D_, itemsF, D_,
              itemsB, D_, S_, D_, H_, 13);
        gemmM(stream, hB, 1536, wQT + (size_t)l * H_ * H_, b_q + l * H_, nullptr, 0, qrB, 1536,
              S_, H_, H_, 9);
        gemmM(stream, itemsB, D_, rh1T + (size_t)l * 2 * D_ * D_, rh_b1 + l * 2 * D_, nullptr, 0,
              k1B, 2 * D_, S_, 2 * D_, D_, 11);
        gemmM(stream, k1B, 2 * D_, rh2T + (size_t)l * D_ * 2 * D_, rh_b2 + l * D_, keysF, D_,
              nullptr, 0, S_, D_, 2 * D_, 5);
        memt_kernel<<<128, 256, 0, stream>>>(fast0, slow0, memT);
        attn_kernel<<<S_ / 4, 256, 0, stream>>>(keysF, memT, fast0, slow0, qrB, hrB);
        gemmM(stream, hrB, 1536, gWT + (size_t)l * 64 * 1536, gate_b + l * 64, gRawF, 64,
              nullptr, 0, S_, 64, 1536, 5);
        sigcoef_kernel<<<S_ * SLn / 256, 256, 0, stream>>>(gRawF, coefF, gaF, gbF);
        scan_part_kernel<<<256, 256, 0, stream>>>(itemsF, gaF, gbF, pF, pS);
        scan_reduce_kernel<<<64, 256, 0, stream>>>(
            pF, pS, coefF, fast0, slow0, outP + LOGITS_N + (size_t)l * SLn * D_,
            outP + LOGITS_N + (size_t)Lc * SLn * D_ + (size_t)l * SLn * D_);
        gemmM(stream, qrB, 1536, wOutT + (size_t)l * H_ * 1536, b_out + l * H_, outF, H_,
              nullptr, 0, S_, H_, 1536, 5);
        ln_kernel<<<S_, 256, 0, stream>>>(hF, outF, ln1_g + l * H_, ln1_b + l * H_, hF, hB, 1536);
        gemmM(stream, hB, 1536, f1T + (size_t)l * I_ * H_, ffn_b1 + l * I_, nullptr, 0, ffn1B,
              I_, S_, I_, H_, 11);
        gemmM(stream, ffn1B, I_, f2T + (size_t)l * H_ * I_, ffn_b2 + l * H_, outF, H_, nullptr,
              0, S_, H_, I_, 5);
        ln_kernel<<<S_, 256, 0, stream>>>(hF, outF, ln2_g + l * H_, ln2_b + l * H_, hF, hB, 1536);
    }
    ln_kernel<<<S_, 256, 0, stream>>>(hF, nullptr, fln_g, fln_b, nullptr, hB, 1536);
    // logits: 256x256 8-wave instance, grid 8x125 = 1000
    gemm_p5<256, 256, 512, 2, 4, 4><<<1000, 512, 0, stream>>>(hB, 1536, embB, nullptr, outP, V_,
                                                              nullptr, 0, H_, 8, 125);
}